// Round 5
// baseline (422.553 us; speedup 1.0000x reference)
//
#include <hip/hip_runtime.h>
#include <hip/hip_bf16.h>
#include <hip/hip_cooperative_groups.h>
#include <stdint.h>

namespace cg = cooperative_groups;

#define BB 32
#define NN 1024
#define CC 1024
#define LL 16

typedef __attribute__((ext_vector_type(4))) float f32x4;
typedef __attribute__((ext_vector_type(8))) short short8;
typedef __attribute__((ext_vector_type(4))) unsigned short ushort4v;

__device__ __forceinline__ unsigned short f2bf(float f) {
  union { float f; unsigned u; } v; v.f = f;
  unsigned r = v.u + 0x7FFF + ((v.u >> 16) & 1);
  return (unsigned short)(r >> 16);
}
__device__ __forceinline__ float bf2f(unsigned short h) {
  union { unsigned u; float f; } v; v.u = ((unsigned)h) << 16; return v.f;
}

// ---------------- weight prep: transpose->bf16 (+ tokW^T, bias pack at z=5) ----------------
__global__ __launch_bounds__(256) void wprep(
    const float* __restrict__ keyW, const float* __restrict__ queryW,
    const float* __restrict__ f1W, const float* __restrict__ f2W,
    const float* __restrict__ kW, const float* __restrict__ qW,
    const float* __restrict__ tokW, const float* __restrict__ keyb,
    const float* __restrict__ queryb,
    unsigned short* __restrict__ WkqT, unsigned short* __restrict__ f1WT,
    unsigned short* __restrict__ f2WT, unsigned short* __restrict__ kWT,
    unsigned short* __restrict__ qWbf, unsigned short* __restrict__ tokWT,
    float* __restrict__ biaskq)
{
  int z = blockIdx.z;
  int tx = threadIdx.x, ty = threadIdx.y;
  if (z == 5) {
    int gid = (blockIdx.y * 32 + blockIdx.x) * 256 + ty * 32 + tx;
    if (gid < 16384) {
      int l = gid >> 10, c = gid & 1023;
      tokWT[gid] = f2bf(tokW[c * 16 + l]);
    } else if (gid < 17408) {
      int i = gid - 16384;
      biaskq[i] = (i < 512) ? keyb[i] : queryb[i - 512];
    }
    return;
  }
  if (z == 4) {
#pragma unroll
    for (int i = 0; i < 4; ++i) {
      int row = blockIdx.y * 32 + ty + 8 * i;
      int col = blockIdx.x * 32 + tx;
      qWbf[row * 1024 + col] = f2bf(qW[row * 1024 + col]);
    }
    return;
  }
  __shared__ float tile[32][33];
  int j0 = blockIdx.x * 32, k0 = blockIdx.y * 32;
  const float* src = (z == 1) ? f1W : (z == 2) ? f2W : kW;
#pragma unroll
  for (int i = 0; i < 4; ++i) {
    int k = k0 + ty + 8 * i;
    int j = j0 + tx;
    float v;
    if (z == 0) v = (j < 512) ? keyW[k * 512 + j] : queryW[k * 512 + (j - 512)];
    else        v = src[k * 1024 + j];
    tile[ty + 8 * i][tx] = v;
  }
  __syncthreads();
  unsigned short* dst = (z == 0) ? WkqT : (z == 1) ? f1WT : (z == 2) ? f2WT : kWT;
#pragma unroll
  for (int i = 0; i < 4; ++i) {
    int j = j0 + ty + 8 * i;
    dst[j * 1024 + k0 + tx] = f2bf(tile[tx][ty + 8 * i]);
  }
}

// ---------------- fused tokenizer: proj MFMA + local softmax + partial T ----------------
// block = (ch, b): 128 pixels. Writes Tp[b][ch][l][c] bf16, Mloc/Sloc[b][ch][l].
__global__ __launch_bounds__(256) void tok_fused(
    const float* __restrict__ X, const unsigned short* __restrict__ tokWT,
    const float* __restrict__ tokB, unsigned short* __restrict__ Tp,
    float* __restrict__ Mloc, float* __restrict__ Sloc)
{
  __shared__ __align__(16) char sp[32768];   // 128 rows x 128 c bf16, swizzled
  __shared__ float E[128][16];
  __shared__ float redm[4][16];
  __shared__ float reds[4][16];
  int tid = threadIdx.x, wid = tid >> 6, lane = tid & 63;
  int lr = lane & 15, hi = lane >> 4;
  int b = blockIdx.y, ch = blockIdx.x;
  int pix0 = b * 1024 + ch * 128;
  int row = tid >> 1, half = tid & 1;
  const float* xr = X + (size_t)(pix0 + row) * 1024 + half * 64;
  const unsigned short* Wb = tokWT + lr * 1024 + hi * 8;
  int wbyte[8];
#pragma unroll
  for (int u = 0; u < 8; ++u)
    wbyte[u] = row * 256 + (((half * 128 + u * 16) ^ ((row & 7) << 4)));
  int arow0 = wid * 32;
  int ar0 = arow0 + lr, ar1 = arow0 + 16 + lr;
  int arb0 = ar0 * 256, arx0 = (ar0 & 7) << 4;
  int arb1 = ar1 * 256, arx1 = (ar1 & 7) << 4;
  f32x4 acc0 = (f32x4)0.f, acc1 = (f32x4)0.f;
  for (int k0 = 0; k0 < 1024; k0 += 128) {
    f32x4 v[16];
#pragma unroll
    for (int i = 0; i < 16; ++i) v[i] = *(const f32x4*)(xr + k0 + i * 4);
    __syncthreads();
#pragma unroll
    for (int u = 0; u < 8; ++u) {
      short8 pk;
      pk[0] = (short)f2bf(v[2*u][0]);   pk[1] = (short)f2bf(v[2*u][1]);
      pk[2] = (short)f2bf(v[2*u][2]);   pk[3] = (short)f2bf(v[2*u][3]);
      pk[4] = (short)f2bf(v[2*u+1][0]); pk[5] = (short)f2bf(v[2*u+1][1]);
      pk[6] = (short)f2bf(v[2*u+1][2]); pk[7] = (short)f2bf(v[2*u+1][3]);
      *(short8*)(sp + wbyte[u]) = pk;
    }
    __syncthreads();
#pragma unroll
    for (int kk = 0; kk < 4; ++kk) {
      short8 bfv = *(const short8*)(Wb + k0 + kk * 32);
      short8 a0 = *(const short8*)(sp + arb0 + (((kk * 64 + hi * 16) ^ arx0)));
      short8 a1 = *(const short8*)(sp + arb1 + (((kk * 64 + hi * 16) ^ arx1)));
      acc0 = __builtin_amdgcn_mfma_f32_16x16x32_bf16(a0, bfv, acc0, 0, 0, 0);
      acc1 = __builtin_amdgcn_mfma_f32_16x16x32_bf16(a1, bfv, acc1, 0, 0, 0);
    }
  }
  // local softmax partials over this chunk's 128 rows, per column l = lr
  float tb = tokB[lr];
  float sv[8];
#pragma unroll
  for (int rr = 0; rr < 4; ++rr) { sv[rr] = acc0[rr] + tb; sv[4 + rr] = acc1[rr] + tb; }
  float pm = sv[0];
#pragma unroll
  for (int i = 1; i < 8; ++i) pm = fmaxf(pm, sv[i]);
  pm = fmaxf(pm, __shfl_xor(pm, 16));
  pm = fmaxf(pm, __shfl_xor(pm, 32));
  if (hi == 0) redm[wid][lr] = pm;
  __syncthreads();
  float m = fmaxf(fmaxf(redm[0][lr], redm[1][lr]), fmaxf(redm[2][lr], redm[3][lr]));
  float ev[8]; float ps = 0.f;
#pragma unroll
  for (int i = 0; i < 8; ++i) { ev[i] = __expf(sv[i] - m); ps += ev[i]; }
  ps += __shfl_xor(ps, 16); ps += __shfl_xor(ps, 32);
  if (hi == 0) reds[wid][lr] = ps;
#pragma unroll
  for (int rr = 0; rr < 4; ++rr) {
    E[arow0 + hi * 4 + rr][lr] = ev[rr];
    E[arow0 + 16 + hi * 4 + rr][lr] = ev[4 + rr];
  }
  __syncthreads();
  if (tid < 16) {
    float sl = reds[0][tid] + reds[1][tid] + reds[2][tid] + reds[3][tid];
    Mloc[(b * 8 + ch) * 16 + tid] = m;   // lane tid has m for col l=tid
    Sloc[(b * 8 + ch) * 16 + tid] = sl;
  }
  // partial T: Tp[l][c] = sum_n E[n][l] * X[n][c]  (X chunk L2-hot)
  f32x4 a16[16];
#pragma unroll
  for (int l = 0; l < 16; ++l) a16[l] = (f32x4)0.f;
  const float* xp = X + (size_t)pix0 * 1024 + tid * 4;
#pragma unroll 4
  for (int n = 0; n < 128; ++n) {
    f32x4 xv = *(const f32x4*)(xp + (size_t)n * 1024);
    const f32x4* ar = (const f32x4*)&E[n][0];
    f32x4 a0 = ar[0], a1 = ar[1], a2 = ar[2], a3 = ar[3];
    a16[0]  += a0[0]*xv; a16[1]  += a0[1]*xv; a16[2]  += a0[2]*xv; a16[3]  += a0[3]*xv;
    a16[4]  += a1[0]*xv; a16[5]  += a1[1]*xv; a16[6]  += a1[2]*xv; a16[7]  += a1[3]*xv;
    a16[8]  += a2[0]*xv; a16[9]  += a2[1]*xv; a16[10] += a2[2]*xv; a16[11] += a2[3]*xv;
    a16[12] += a3[0]*xv; a16[13] += a3[1]*xv; a16[14] += a3[2]*xv; a16[15] += a3[3]*xv;
  }
  unsigned short* op = Tp + ((size_t)(b * 8 + ch) * 16) * 1024 + tid * 4;
#pragma unroll
  for (int l = 0; l < 16; ++l) {
    f32x4 s = a16[l];
    ushort4v h; h[0]=f2bf(s[0]); h[1]=f2bf(s[1]); h[2]=f2bf(s[2]); h[3]=f2bf(s[3]);
    *(ushort4v*)(op + (size_t)l * 1024) = h;
  }
}

// ---------------- chain kernel stages (cooperative) ----------------
struct ChainArgs {
  const unsigned short* Tp; const float* Mloc; const float* Sloc;
  float* Tbuf; unsigned short* Tbf;
  const unsigned short* WkqT; const float* biaskq; float* kqbuf;
  float* Tdash; unsigned short* Tdbf;
  const unsigned short* f1WT; const float* f1B; unsigned short* Hbf;
  const unsigned short* f2WT; const float* f2B; float* Tout; unsigned short* Toutbf;
  const unsigned short* kWT; const float* kB; unsigned short* Tkbf;
  const unsigned short* qWbf; const float* qB; float* rbuf;
  unsigned short* Gtbf;
  const float* X; float* Xout;
};

// S0: merge chunk partials with online-softmax rescale -> T (f32 + bf16)
__device__ __forceinline__ void tmerge_stage(int bid, const ChainArgs& a) {
  int tid = threadIdx.x;
  int g = bid * 2 + (tid >> 7);        // token row in [0,512)
  int b = g >> 4, l = g & 15;
  int j = tid & 127;
  float M = -1e30f;
#pragma unroll
  for (int ch = 0; ch < 8; ++ch) M = fmaxf(M, a.Mloc[(b * 8 + ch) * 16 + l]);
  float w[8]; float denom = 0.f;
#pragma unroll
  for (int ch = 0; ch < 8; ++ch) {
    w[ch] = __expf(a.Mloc[(b * 8 + ch) * 16 + l] - M);
    denom += w[ch] * a.Sloc[(b * 8 + ch) * 16 + l];
  }
  float inv = 1.f / denom;
  float o[8];
#pragma unroll
  for (int t = 0; t < 8; ++t) o[t] = 0.f;
#pragma unroll
  for (int ch = 0; ch < 8; ++ch) {
    const unsigned short* p = a.Tp + ((size_t)((b * 8 + ch) * 16 + l)) * 1024 + j * 8;
    short8 v = *(const short8*)p;
    float wc = w[ch];
#pragma unroll
    for (int t = 0; t < 8; ++t) o[t] += wc * bf2f((unsigned short)v[t]);
  }
  f32x4 o0, o1; short8 hb;
#pragma unroll
  for (int t = 0; t < 4; ++t) {
    float x0 = o[t] * inv, x1 = o[4 + t] * inv;
    o0[t] = x0; o1[t] = x1;
    hb[t] = (short)f2bf(x0); hb[4 + t] = (short)f2bf(x1);
  }
  *(f32x4*)(a.Tbuf + (size_t)g * 1024 + j * 8) = o0;
  *(f32x4*)(a.Tbuf + (size_t)g * 1024 + j * 8 + 4) = o1;
  *(short8*)(a.Tbf + (size_t)g * 1024 + j * 8) = hb;
}

// NT bf16 GEMM stage, M=512, Nn=1024, K=1024, 32x64 tile per block (256 blocks)
template<int RELU, int HAS_BIAS, int HAS_RES, int STORE_F32, int STORE_BF16>
__device__ __forceinline__ void gemm_stage(int bid, char* smem,
    const unsigned short* A, const unsigned short* Bm,
    const float* bias, const float* res, float* outF, unsigned short* outB)
{
  const int K = 1024;
  char* Asp = smem;
  char* Bsp = smem + 4096;
  int tid = threadIdx.x, wid = tid >> 6, lane = tid & 63;
  int lr = lane & 15, hi = lane >> 4;
  int m0 = (bid & 15) * 32, n0 = (bid >> 4) * 64;
  int arow = tid >> 3, acol = (tid & 7) * 8;
  int brow = tid >> 2, bcol = (tid & 3) * 16;
  const unsigned short* Ap = A + (size_t)(m0 + arow) * K + acol;
  const unsigned short* Bp = Bm + (size_t)(n0 + brow) * K + bcol;
  int aw  = arow * 128 + (((acol * 2) ^ ((arow & 7) << 4)));
  int bw0 = brow * 128 + (((bcol * 2) ^ ((brow & 7) << 4)));
  int bw1 = brow * 128 + ((((bcol * 2) + 16) ^ ((brow & 7) << 4)));
  short8 aR[2]; short8 bR[2][2];
  aR[0]    = *(const short8*)(Ap);
  bR[0][0] = *(const short8*)(Bp);
  bR[0][1] = *(const short8*)(Bp + 8);
  aR[1]    = *(const short8*)(Ap + 64);
  bR[1][0] = *(const short8*)(Bp + 64);
  bR[1][1] = *(const short8*)(Bp + 72);
  f32x4 acc[2];
  acc[0] = (f32x4)0.f; acc[1] = (f32x4)0.f;
  int wm = (wid >> 1) * 16, wn = (wid & 1) * 32;
  int arb = (wm + lr) * 128, arx = ((wm + lr) & 7) << 4;
  for (int s = 0; s < 16; ++s) {
    __syncthreads();
    *(short8*)(Asp + aw)  = aR[s & 1];
    *(short8*)(Bsp + bw0) = bR[s & 1][0];
    *(short8*)(Bsp + bw1) = bR[s & 1][1];
    __syncthreads();
    if (s + 2 < 16) {
      int k0 = (s + 2) * 64;
      aR[s & 1]    = *(const short8*)(Ap + k0);
      bR[s & 1][0] = *(const short8*)(Bp + k0);
      bR[s & 1][1] = *(const short8*)(Bp + k0 + 8);
    }
#pragma unroll
    for (int kk = 0; kk < 2; ++kk) {
      short8 af = *(const short8*)(Asp + arb + (((kk * 64 + hi * 16) ^ arx)));
#pragma unroll
      for (int sn = 0; sn < 2; ++sn) {
        int br = wn + sn * 16 + lr;
        short8 bf = *(const short8*)(Bsp + br * 128 + (((kk * 64 + hi * 16) ^ ((br & 7) << 4))));
        acc[sn] = __builtin_amdgcn_mfma_f32_16x16x32_bf16(af, bf, acc[sn], 0, 0, 0);
      }
    }
  }
  int row0 = m0 + wm + hi * 4;
#pragma unroll
  for (int sn = 0; sn < 2; ++sn) {
    int col = n0 + wn + sn * 16 + lr;
    float bv_ = HAS_BIAS ? bias[col] : 0.f;
#pragma unroll
    for (int rr = 0; rr < 4; ++rr) {
      float x = acc[sn][rr] + bv_;
      if (RELU) x = fmaxf(x, 0.f);
      size_t idx = (size_t)(row0 + rr) * 1024 + col;
      if (HAS_RES) x += res[idx];
      if (STORE_F32) outF[idx] = x;
      if (STORE_BF16) outB[idx] = f2bf(x);
    }
  }
}

// S2: token self-attn scores + softmax + T_dash; bid -> (b = bid>>3, cs = bid&7)
__device__ __forceinline__ void scores_stage(int bid, char* smem, const ChainArgs& a) {
  float (*Ts)[128] = (float(*)[128])smem;
  int cs = bid & 7, b = bid >> 3;
  int c0 = cs * 128;
  int tid = threadIdx.x, lane = tid & 63;
#pragma unroll
  for (int i = 0; i < 2; ++i) {
    int fi = tid + 256 * i;
    int rrow = fi >> 5, c4 = (fi & 31) * 4;
    *(f32x4*)&Ts[rrow][c4] = *(const f32x4*)&a.Tbuf[((size_t)b * 16 + rrow) * 1024 + c0 + c4];
  }
  __syncthreads();
  int l = tid >> 4, m = tid & 15;
  const float* krow = a.kqbuf + ((size_t)b * 16 + l) * 1024;
  const float* qrow = a.kqbuf + ((size_t)b * 16 + m) * 1024 + 512;
  float s = 0.f;
#pragma unroll 8
  for (int d = 0; d < 512; d += 4) {
    f32x4 kv = *(const f32x4*)(krow + d);
    f32x4 qv = *(const f32x4*)(qrow + d);
    s += kv[0]*qv[0] + kv[1]*qv[1] + kv[2]*qv[2] + kv[3]*qv[3];
  }
  float mx = s;
  mx = fmaxf(mx, __shfl_xor(mx, 1)); mx = fmaxf(mx, __shfl_xor(mx, 2));
  mx = fmaxf(mx, __shfl_xor(mx, 4)); mx = fmaxf(mx, __shfl_xor(mx, 8));
  float e = __expf(s - mx);
  float sum = e;
  sum += __shfl_xor(sum, 1); sum += __shfl_xor(sum, 2);
  sum += __shfl_xor(sum, 4); sum += __shfl_xor(sum, 8);
  float pv = e / sum;
  float pl[16];
#pragma unroll
  for (int i = 0; i < 16; ++i) pl[i] = __shfl(pv, (lane & 48) + i);
  float* od = a.Tdash + ((size_t)b * 16 + l) * 1024 + c0;
  unsigned short* ob = a.Tdbf + ((size_t)b * 16 + l) * 1024 + c0;
#pragma unroll
  for (int h = 0; h < 2; ++h) {
    int c = m * 8 + h * 4;
    f32x4 o = *(const f32x4*)&Ts[l][c];
#pragma unroll
    for (int mm = 0; mm < 16; ++mm) {
      f32x4 tv = *(const f32x4*)&Ts[mm][c];
      o += pl[mm] * tv;
    }
    *(f32x4*)(od + c) = o;
    ushort4v hh; hh[0]=f2bf(o[0]); hh[1]=f2bf(o[1]); hh[2]=f2bf(o[2]); hh[3]=f2bf(o[3]);
    *(ushort4v*)(ob + c) = hh;
  }
}

// r[m] = qB . Tk[m,:]  (blocks bid<16, 32 rows each)
__device__ __forceinline__ void r_stage(int bid, const ChainArgs& a) {
  int tid = threadIdx.x, wid = tid >> 6, lane = tid & 63;
#pragma unroll
  for (int rw = 0; rw < 8; ++rw) {
    int m = bid * 32 + wid * 8 + rw;
    const unsigned short* p = a.Tkbf + (size_t)m * 1024 + lane * 16;
    short8 v0 = *(const short8*)p;
    short8 v1 = *(const short8*)(p + 8);
    float s = 0.f;
#pragma unroll
    for (int j = 0; j < 8; ++j) {
      s += bf2f((unsigned short)v0[j]) * a.qB[lane * 16 + j];
      s += bf2f((unsigned short)v1[j]) * a.qB[lane * 16 + 8 + j];
    }
#pragma unroll
    for (int msk = 32; msk >= 1; msk >>= 1) s += __shfl_xor(s, msk);
    if (lane == 0) a.rbuf[m] = s;
  }
}

// S7: fused sim + out on 128-pixel chunk; bid -> (b = bid>>3, ch = bid&7)
__device__ __forceinline__ void simout_stage(int bid, char* smem, const ChainArgs& a) {
  char* sp = smem;                       // 32KB X stage
  float (*Ps)[16] = (float(*)[16])(smem + 32768);   // 8KB
  int tid = threadIdx.x, wid = tid >> 6, lane = tid & 63;
  int lr = lane & 15, hi = lane >> 4;
  int b = bid >> 3, ch = bid & 7;
  int pix0 = b * 1024 + ch * 128;
  int row = tid >> 1, half = tid & 1;
  const float* xr = a.X + (size_t)(pix0 + row) * 1024 + half * 64;
  const unsigned short* Wb = a.Gtbf + (size_t)b * 16 * 1024 + (size_t)lr * 1024 + hi * 8;
  int wbyte[8];
#pragma unroll
  for (int u = 0; u < 8; ++u)
    wbyte[u] = row * 256 + (((half * 128 + u * 16) ^ ((row & 7) << 4)));
  int arow0 = wid * 32;
  int ar0 = arow0 + lr, ar1 = arow0 + 16 + lr;
  int arb0 = ar0 * 256, arx0 = (ar0 & 7) << 4;
  int arb1 = ar1 * 256, arx1 = (ar1 & 7) << 4;
  f32x4 acc0 = (f32x4)0.f, acc1 = (f32x4)0.f;
  for (int k0 = 0; k0 < 1024; k0 += 128) {
    f32x4 v[16];
#pragma unroll
    for (int i = 0; i < 16; ++i) v[i] = *(const f32x4*)(xr + k0 + i * 4);
    __syncthreads();
#pragma unroll
    for (int u = 0; u < 8; ++u) {
      short8 pk;
      pk[0] = (short)f2bf(v[2*u][0]);   pk[1] = (short)f2bf(v[2*u][1]);
      pk[2] = (short)f2bf(v[2*u][2]);   pk[3] = (short)f2bf(v[2*u][3]);
      pk[4] = (short)f2bf(v[2*u+1][0]); pk[5] = (short)f2bf(v[2*u+1][1]);
      pk[6] = (short)f2bf(v[2*u+1][2]); pk[7] = (short)f2bf(v[2*u+1][3]);
      *(short8*)(sp + wbyte[u]) = pk;
    }
    __syncthreads();
#pragma unroll
    for (int kk = 0; kk < 4; ++kk) {
      short8 bfv = *(const short8*)(Wb + k0 + kk * 32);
      short8 a0 = *(const short8*)(sp + arb0 + (((kk * 64 + hi * 16) ^ arx0)));
      short8 a1 = *(const short8*)(sp + arb1 + (((kk * 64 + hi * 16) ^ arx1)));
      acc0 = __builtin_amdgcn_mfma_f32_16x16x32_bf16(a0, bfv, acc0, 0, 0, 0);
      acc1 = __builtin_amdgcn_mfma_f32_16x16x32_bf16(a1, bfv, acc1, 0, 0, 0);
    }
  }
  float bv = a.rbuf[b * 16 + lr];
#pragma unroll
  for (int q = 0; q < 8; ++q) {
    float vv = (q < 4 ? acc0[q] : acc1[q - 4]) + bv;
    float mx = vv;
    mx = fmaxf(mx, __shfl_xor(mx, 1)); mx = fmaxf(mx, __shfl_xor(mx, 2));
    mx = fmaxf(mx, __shfl_xor(mx, 4)); mx = fmaxf(mx, __shfl_xor(mx, 8));
    float e = __expf(vv - mx);
    float ss = e;
    ss += __shfl_xor(ss, 1); ss += __shfl_xor(ss, 2);
    ss += __shfl_xor(ss, 4); ss += __shfl_xor(ss, 8);
    Ps[arow0 + (q < 4 ? 0 : 16) + hi * 4 + (q & 3)][lr] = e / ss;
  }
  __syncthreads();
  int c4 = tid * 4;
  f32x4 tsr[16];
#pragma unroll
  for (int l = 0; l < 16; ++l)
    tsr[l] = *(const f32x4*)&a.Tout[((size_t)b * 16 + l) * 1024 + c4];
  const float* xp = a.X + (size_t)pix0 * 1024 + c4;
  float* op = a.Xout + (size_t)pix0 * 1024 + c4;
#pragma unroll 2
  for (int n = 0; n < 128; ++n) {
    f32x4 xv = *(const f32x4*)(xp + (size_t)n * 1024);
    const f32x4* pr = (const f32x4*)&Ps[n][0];
    f32x4 p0 = pr[0], p1 = pr[1], p2 = pr[2], p3 = pr[3];
    f32x4 o = xv;
    o += p0[0]*tsr[0];  o += p0[1]*tsr[1];  o += p0[2]*tsr[2];  o += p0[3]*tsr[3];
    o += p1[0]*tsr[4];  o += p1[1]*tsr[5];  o += p1[2]*tsr[6];  o += p1[3]*tsr[7];
    o += p2[0]*tsr[8];  o += p2[1]*tsr[9];  o += p2[2]*tsr[10]; o += p2[3]*tsr[11];
    o += p3[0]*tsr[12]; o += p3[1]*tsr[13]; o += p3[2]*tsr[14]; o += p3[3]*tsr[15];
    __builtin_nontemporal_store(o, (f32x4*)(op + (size_t)n * 1024));
  }
}

__global__ __launch_bounds__(256) void chain_kernel(ChainArgs a) {
  cg::grid_group gg = cg::this_grid();
  __shared__ __align__(16) char smem[40960];
  int bid = blockIdx.x;
  tmerge_stage(bid, a);
  gg.sync();
  gemm_stage<0,1,0,1,0>(bid, smem, a.Tbf, a.WkqT, a.biaskq, nullptr, a.kqbuf, nullptr);
  gg.sync();
  scores_stage(bid, smem, a);
  gg.sync();
  gemm_stage<1,1,0,0,1>(bid, smem, a.Tdbf, a.f1WT, a.f1B, nullptr, nullptr, a.Hbf);
  gg.sync();
  gemm_stage<0,1,1,1,1>(bid, smem, a.Hbf, a.f2WT, a.f2B, a.Tdash, a.Tout, a.Toutbf);
  gg.sync();
  gemm_stage<0,1,0,0,1>(bid, smem, a.Toutbf, a.kWT, a.kB, nullptr, nullptr, a.Tkbf);
  gg.sync();
  gemm_stage<0,0,0,0,1>(bid, smem, a.Tkbf, a.qWbf, nullptr, nullptr, nullptr, a.Gtbf);
  if (bid < 16) r_stage(bid, a);
  gg.sync();
  simout_stage(bid, smem, a);
}

extern "C" void kernel_launch(void* const* d_in, const int* in_sizes, int n_in,
                              void* d_out, int out_size, void* d_ws, size_t ws_size,
                              hipStream_t stream)
{
  const float* X      = (const float*)d_in[0];
  const float* tokW   = (const float*)d_in[2];
  const float* tokB   = (const float*)d_in[3];
  const float* keyW   = (const float*)d_in[4];
  const float* keyB   = (const float*)d_in[5];
  const float* queryW = (const float*)d_in[6];
  const float* queryB = (const float*)d_in[7];
  const float* f1W    = (const float*)d_in[8];
  const float* f1B    = (const float*)d_in[9];
  const float* f2W    = (const float*)d_in[10];
  const float* f2B    = (const float*)d_in[11];
  const float* qW     = (const float*)d_in[12];
  const float* qB     = (const float*)d_in[13];
  const float* kW     = (const float*)d_in[14];
  const float* kB     = (const float*)d_in[15];

  float* Xout = (float*)d_out;
  float* Tout = (float*)d_out + (size_t)BB * NN * CC;

  char* ws = (char*)d_ws;
  size_t off = 0;
  auto alloc_f = [&](size_t n) { float* pp = (float*)(ws + off); off += n * 4; return pp; };
  float* Tbuf   = alloc_f(524288);
  float* kqbuf  = alloc_f(524288);
  float* Tdash  = alloc_f(524288);
  float* rbuf   = alloc_f(1024);
  float* biaskq = alloc_f(1024);
  float* Mloc   = alloc_f(4096);
  float* Sloc   = alloc_f(4096);
  auto alloc_h = [&](size_t n) { unsigned short* pp = (unsigned short*)(ws + off); off += n * 2; return pp; };
  unsigned short* Tp     = alloc_h(4194304);   // [B][8][L][C] bf16
  unsigned short* Tbf    = alloc_h(524288);
  unsigned short* Tdbf   = alloc_h(524288);
  unsigned short* Hbf    = alloc_h(524288);
  unsigned short* Toutbf = alloc_h(524288);
  unsigned short* Tkbf   = alloc_h(524288);
  unsigned short* Gtbf   = alloc_h(524288);
  unsigned short* WkqT   = alloc_h(1048576);
  unsigned short* f1WT   = alloc_h(1048576);
  unsigned short* f2WT   = alloc_h(1048576);
  unsigned short* kWT    = alloc_h(1048576);
  unsigned short* qWbf   = alloc_h(1048576);
  unsigned short* tokWT  = alloc_h(16384);
  (void)ws_size; (void)in_sizes; (void)n_in; (void)out_size;

  wprep<<<dim3(32, 32, 6), dim3(32, 8), 0, stream>>>(keyW, queryW, f1W, f2W, kW, qW,
                                                     tokW, keyB, queryB,
                                                     WkqT, f1WT, f2WT, kWT, qWbf, tokWT, biaskq);
  tok_fused<<<dim3(8, 32), 256, 0, stream>>>(X, tokWT, tokB, Tp, Mloc, Sloc);

  ChainArgs ca;
  ca.Tp = Tp; ca.Mloc = Mloc; ca.Sloc = Sloc;
  ca.Tbuf = Tbuf; ca.Tbf = Tbf;
  ca.WkqT = WkqT; ca.biaskq = biaskq; ca.kqbuf = kqbuf;
  ca.Tdash = Tdash; ca.Tdbf = Tdbf;
  ca.f1WT = f1WT; ca.f1B = f1B; ca.Hbf = Hbf;
  ca.f2WT = f2WT; ca.f2B = f2B; ca.Tout = Tout; ca.Toutbf = Toutbf;
  ca.kWT = kWT; ca.kB = kB; ca.Tkbf = Tkbf;
  ca.qWbf = qWbf; ca.qB = qB; ca.rbuf = rbuf;
  ca.Gtbf = Gtbf;
  ca.X = X; ca.Xout = Xout;
  void* kp[] = { &ca };
  hipLaunchCooperativeKernel((void*)chain_kernel, dim3(256), dim3(256), kp, 0, stream);
}

// Round 6
// 410.649 us; speedup vs baseline: 1.0290x; 1.0290x over previous
//
#include <hip/hip_runtime.h>
#include <hip/hip_bf16.h>
#include <stdint.h>

#define BB 32
#define NN 1024
#define CC 1024
#define LL 16

typedef __attribute__((ext_vector_type(4))) float f32x4;
typedef __attribute__((ext_vector_type(8))) short short8;
typedef __attribute__((ext_vector_type(4))) unsigned short ushort4v;

__device__ __forceinline__ unsigned short f2bf(float f) {
  union { float f; unsigned u; } v; v.f = f;
  unsigned r = v.u + 0x7FFF + ((v.u >> 16) & 1);
  return (unsigned short)(r >> 16);
}
__device__ __forceinline__ float bf2f(unsigned short h) {
  union { unsigned u; float f; } v; v.u = ((unsigned)h) << 16; return v.f;
}

// ---------------- weight prep: transpose->bf16 (+ tokW^T, bias pack at z=5) ----------------
__global__ __launch_bounds__(256) void wprep(
    const float* __restrict__ keyW, const float* __restrict__ queryW,
    const float* __restrict__ f1W, const float* __restrict__ f2W,
    const float* __restrict__ kW, const float* __restrict__ qW,
    const float* __restrict__ tokW, const float* __restrict__ keyb,
    const float* __restrict__ queryb,
    unsigned short* __restrict__ WkqT, unsigned short* __restrict__ f1WT,
    unsigned short* __restrict__ f2WT, unsigned short* __restrict__ kWT,
    unsigned short* __restrict__ qWbf, unsigned short* __restrict__ tokWT,
    float* __restrict__ biaskq)
{
  int z = blockIdx.z;
  int tx = threadIdx.x, ty = threadIdx.y;
  if (z == 5) {
    int gid = (blockIdx.y * 32 + blockIdx.x) * 256 + ty * 32 + tx;
    if (gid < 16384) {
      int l = gid >> 10, c = gid & 1023;
      tokWT[gid] = f2bf(tokW[c * 16 + l]);
    } else if (gid < 17408) {
      int i = gid - 16384;
      biaskq[i] = (i < 512) ? keyb[i] : queryb[i - 512];
    }
    return;
  }
  if (z == 4) {
#pragma unroll
    for (int i = 0; i < 4; ++i) {
      int row = blockIdx.y * 32 + ty + 8 * i;
      int col = blockIdx.x * 32 + tx;
      qWbf[row * 1024 + col] = f2bf(qW[row * 1024 + col]);
    }
    return;
  }
  __shared__ float tile[32][33];
  int j0 = blockIdx.x * 32, k0 = blockIdx.y * 32;
  const float* src = (z == 1) ? f1W : (z == 2) ? f2W : kW;
#pragma unroll
  for (int i = 0; i < 4; ++i) {
    int k = k0 + ty + 8 * i;
    int j = j0 + tx;
    float v;
    if (z == 0) v = (j < 512) ? keyW[k * 512 + j] : queryW[k * 512 + (j - 512)];
    else        v = src[k * 1024 + j];
    tile[ty + 8 * i][tx] = v;
  }
  __syncthreads();
  unsigned short* dst = (z == 0) ? WkqT : (z == 1) ? f1WT : (z == 2) ? f2WT : kWT;
#pragma unroll
  for (int i = 0; i < 4; ++i) {
    int j = j0 + ty + 8 * i;
    dst[j * 1024 + k0 + tx] = f2bf(tile[tx][ty + 8 * i]);
  }
}

// ---------------- fused tokenizer: proj MFMA + chunk-local softmax + partial T ----------------
// block = (ch<16, b): 64 pixels. Tp[b][ch][l][c] bf16, Mloc/Sloc[(b*16+ch)*16+l].
__global__ __launch_bounds__(256) void tok_fused(
    const float* __restrict__ X, const unsigned short* __restrict__ tokWT,
    const float* __restrict__ tokB, unsigned short* __restrict__ Tp,
    float* __restrict__ Mloc, float* __restrict__ Sloc)
{
  __shared__ __align__(16) char sp[16384];   // 64 rows x 128 c bf16, XOR-swizzled
  __shared__ float E[64][16];
  __shared__ float redm[4][16];
  __shared__ float reds[4][16];
  int tid = threadIdx.x, wid = tid >> 6, lane = tid & 63;
  int lr = lane & 15, hi = lane >> 4;
  int b = blockIdx.y, ch = blockIdx.x;
  int pix0 = b * 1024 + ch * 64;
  int row = tid >> 2, seg = tid & 3;
  const float* xr = X + (size_t)(pix0 + row) * 1024 + seg * 32;
  const unsigned short* Wb = tokWT + lr * 1024 + hi * 8;
  int wbyte[4];
#pragma unroll
  for (int u = 0; u < 4; ++u)
    wbyte[u] = row * 256 + (((seg * 64 + u * 16) ^ ((row & 7) << 4)));
  int arow = wid * 16 + lr;
  int rbyte = arow * 256;
  int rx = (arow & 7) << 4;
  f32x4 acc = (f32x4)0.f;
  for (int k0 = 0; k0 < 1024; k0 += 128) {
    f32x4 v[8];
#pragma unroll
    for (int i = 0; i < 8; ++i) v[i] = *(const f32x4*)(xr + k0 + i * 4);
    __syncthreads();
#pragma unroll
    for (int u = 0; u < 4; ++u) {
      short8 pk;
      pk[0] = (short)f2bf(v[2*u][0]);   pk[1] = (short)f2bf(v[2*u][1]);
      pk[2] = (short)f2bf(v[2*u][2]);   pk[3] = (short)f2bf(v[2*u][3]);
      pk[4] = (short)f2bf(v[2*u+1][0]); pk[5] = (short)f2bf(v[2*u+1][1]);
      pk[6] = (short)f2bf(v[2*u+1][2]); pk[7] = (short)f2bf(v[2*u+1][3]);
      *(short8*)(sp + wbyte[u]) = pk;
    }
    __syncthreads();
#pragma unroll
    for (int kk = 0; kk < 4; ++kk) {
      short8 af = *(const short8*)(sp + rbyte + (((kk * 64 + hi * 16) ^ rx)));
      short8 bfv = *(const short8*)(Wb + k0 + kk * 32);
      acc = __builtin_amdgcn_mfma_f32_16x16x32_bf16(af, bfv, acc, 0, 0, 0);
    }
  }
  // chunk-local softmax partials over 64 rows, per column l = lr
  float tb = tokB[lr];
  float sv[4];
#pragma unroll
  for (int rr = 0; rr < 4; ++rr) sv[rr] = acc[rr] + tb;
  float pm = fmaxf(fmaxf(sv[0], sv[1]), fmaxf(sv[2], sv[3]));
  pm = fmaxf(pm, __shfl_xor(pm, 16));
  pm = fmaxf(pm, __shfl_xor(pm, 32));
  if (hi == 0) redm[wid][lr] = pm;
  __syncthreads();
  float m = fmaxf(fmaxf(redm[0][lr], redm[1][lr]), fmaxf(redm[2][lr], redm[3][lr]));
  float ev[4]; float ps = 0.f;
#pragma unroll
  for (int i = 0; i < 4; ++i) { ev[i] = __expf(sv[i] - m); ps += ev[i]; }
  ps += __shfl_xor(ps, 16); ps += __shfl_xor(ps, 32);
  if (hi == 0) reds[wid][lr] = ps;
#pragma unroll
  for (int rr = 0; rr < 4; ++rr)
    E[wid * 16 + hi * 4 + rr][lr] = ev[rr];
  __syncthreads();
  if (tid < 16) {
    float sl = reds[0][tid] + reds[1][tid] + reds[2][tid] + reds[3][tid];
    Mloc[(b * 16 + ch) * 16 + tid] = m;
    Sloc[(b * 16 + ch) * 16 + tid] = sl;
  }
  // partial T: Tp[l][c] = sum_n E[n][l] * X[n][c]  (chunk X is L2-hot)
  f32x4 a16[16];
#pragma unroll
  for (int l = 0; l < 16; ++l) a16[l] = (f32x4)0.f;
  const float* xp = X + (size_t)pix0 * 1024 + tid * 4;
  for (int n0 = 0; n0 < 64; n0 += 8) {
    f32x4 xv[8];
#pragma unroll
    for (int i = 0; i < 8; ++i) xv[i] = *(const f32x4*)(xp + (size_t)(n0 + i) * 1024);
#pragma unroll
    for (int i = 0; i < 8; ++i) {
      const f32x4* ar = (const f32x4*)&E[n0 + i][0];
      f32x4 a0 = ar[0], a1 = ar[1], a2 = ar[2], a3 = ar[3];
      f32x4 x0 = xv[i];
      a16[0]  += a0[0]*x0; a16[1]  += a0[1]*x0; a16[2]  += a0[2]*x0; a16[3]  += a0[3]*x0;
      a16[4]  += a1[0]*x0; a16[5]  += a1[1]*x0; a16[6]  += a1[2]*x0; a16[7]  += a1[3]*x0;
      a16[8]  += a2[0]*x0; a16[9]  += a2[1]*x0; a16[10] += a2[2]*x0; a16[11] += a2[3]*x0;
      a16[12] += a3[0]*x0; a16[13] += a3[1]*x0; a16[14] += a3[2]*x0; a16[15] += a3[3]*x0;
    }
  }
  unsigned short* op = Tp + ((size_t)(b * 16 + ch) * 16) * 1024 + tid * 4;
#pragma unroll
  for (int l = 0; l < 16; ++l) {
    f32x4 s = a16[l];
    ushort4v h; h[0]=f2bf(s[0]); h[1]=f2bf(s[1]); h[2]=f2bf(s[2]); h[3]=f2bf(s[3]);
    *(ushort4v*)(op + (size_t)l * 1024) = h;
  }
}

// ---------------- merge 16 chunk partials with online-softmax rescale ----------------
__global__ __launch_bounds__(256) void tmerge(
    const unsigned short* __restrict__ Tp, const float* __restrict__ Mloc,
    const float* __restrict__ Sloc, float* __restrict__ T,
    unsigned short* __restrict__ Tbf)
{
  int tid = threadIdx.x;
  int g = blockIdx.x * 2 + (tid >> 7);    // token row in [0,512)
  int b = g >> 4, l = g & 15;
  int j = tid & 127;
  float M = -1e30f;
#pragma unroll
  for (int ch = 0; ch < 16; ++ch) M = fmaxf(M, Mloc[(b * 16 + ch) * 16 + l]);
  float w[16]; float denom = 0.f;
#pragma unroll
  for (int ch = 0; ch < 16; ++ch) {
    w[ch] = __expf(Mloc[(b * 16 + ch) * 16 + l] - M);
    denom += w[ch] * Sloc[(b * 16 + ch) * 16 + l];
  }
  float inv = 1.f / denom;
  float o[8];
#pragma unroll
  for (int t = 0; t < 8; ++t) o[t] = 0.f;
#pragma unroll
  for (int ch = 0; ch < 16; ++ch) {
    const unsigned short* p = Tp + ((size_t)((b * 16 + ch) * 16 + l)) * 1024 + j * 8;
    short8 v = *(const short8*)p;
    float wc = w[ch];
#pragma unroll
    for (int t = 0; t < 8; ++t) o[t] += wc * bf2f((unsigned short)v[t]);
  }
  f32x4 o0, o1; short8 hb;
#pragma unroll
  for (int t = 0; t < 4; ++t) {
    float x0 = o[t] * inv, x1 = o[4 + t] * inv;
    o0[t] = x0; o1[t] = x1;
    hb[t] = (short)f2bf(x0); hb[4 + t] = (short)f2bf(x1);
  }
  *(f32x4*)(T + (size_t)g * 1024 + j * 8) = o0;
  *(f32x4*)(T + (size_t)g * 1024 + j * 8 + 4) = o1;
  *(short8*)(Tbf + (size_t)g * 1024 + j * 8) = hb;
}

// ---------------- NT bf16 GEMM, M=512, Nn=1024, K=1024, 32x32 tiles (512 blocks) ----------------
template<int RELU, int HAS_BIAS, int HAS_RES, int STORE_F32, int STORE_BF16>
__global__ __launch_bounds__(256) void gemm32x32(
    const unsigned short* __restrict__ A, const unsigned short* __restrict__ Bm,
    const float* __restrict__ bias, const float* __restrict__ res,
    float* __restrict__ outF, unsigned short* __restrict__ outB)
{
  const int K = 1024;
  __shared__ __align__(16) char sh[8192];   // As 4KB | Bs 4KB, XOR-swizzled rows of 128B
  char* Asp = sh;
  char* Bsp = sh + 4096;
  int tid = threadIdx.x, wid = tid >> 6, lane = tid & 63;
  int lr = lane & 15, hi = lane >> 4;
  int m0 = blockIdx.x * 32, n0 = blockIdx.y * 32;
  int srow = tid >> 3, scol = (tid & 7) * 8;   // 32 rows x 64 k
  const unsigned short* Ap = A + (size_t)(m0 + srow) * K + scol;
  const unsigned short* Bp = Bm + (size_t)(n0 + srow) * K + scol;
  int sw = srow * 128 + (((scol * 2) ^ ((srow & 7) << 4)));
  short8 aR[2], bR[2];
  aR[0] = *(const short8*)(Ap);
  bR[0] = *(const short8*)(Bp);
  aR[1] = *(const short8*)(Ap + 64);
  bR[1] = *(const short8*)(Bp + 64);
  f32x4 acc = (f32x4)0.f;
  int wm = (wid >> 1) * 16, wn = (wid & 1) * 16;
  int ar = wm + lr, br = wn + lr;
  int arb = ar * 128, arx = (ar & 7) << 4;
  int brb = br * 128, brx = (br & 7) << 4;
  for (int s = 0; s < 16; ++s) {
    __syncthreads();
    *(short8*)(Asp + sw) = aR[s & 1];
    *(short8*)(Bsp + sw) = bR[s & 1];
    __syncthreads();
    if (s + 2 < 16) {
      int k0 = (s + 2) * 64;
      aR[s & 1] = *(const short8*)(Ap + k0);
      bR[s & 1] = *(const short8*)(Bp + k0);
    }
#pragma unroll
    for (int kk = 0; kk < 2; ++kk) {
      short8 af = *(const short8*)(Asp + arb + (((kk * 64 + hi * 16) ^ arx)));
      short8 bf = *(const short8*)(Bsp + brb + (((kk * 64 + hi * 16) ^ brx)));
      acc = __builtin_amdgcn_mfma_f32_16x16x32_bf16(af, bf, acc, 0, 0, 0);
    }
  }
  int row0 = m0 + wm + hi * 4;
  int col = n0 + wn + lr;
  float bv_ = HAS_BIAS ? bias[col] : 0.f;
#pragma unroll
  for (int rr = 0; rr < 4; ++rr) {
    float x = acc[rr] + bv_;
    if (RELU) x = fmaxf(x, 0.f);
    size_t idx = (size_t)(row0 + rr) * 1024 + col;
    if (HAS_RES) x += res[idx];
    if (STORE_F32) outF[idx] = x;
    if (STORE_BF16) outB[idx] = f2bf(x);
  }
}

// ---------------- token self-attn: scores + softmax + T_dash (c-split 8) ----------------
__global__ __launch_bounds__(256) void scores_tdash(
    const float* __restrict__ kq, const float* __restrict__ T,
    float* __restrict__ Tdash, unsigned short* __restrict__ Tdbf)
{
  int cs = blockIdx.x, b = blockIdx.y;
  int c0 = cs * 128;
  __shared__ float Ts[16][128];
  int tid = threadIdx.x, lane = tid & 63;
#pragma unroll
  for (int i = 0; i < 2; ++i) {
    int fi = tid + 256 * i;            // f4 over 512
    int rrow = fi >> 5, c4 = (fi & 31) * 4;
    *(f32x4*)&Ts[rrow][c4] = *(const f32x4*)&T[((size_t)b * 16 + rrow) * 1024 + c0 + c4];
  }
  __syncthreads();
  int l = tid >> 4, m = tid & 15;
  const float* krow = kq + ((size_t)b * 16 + l) * 1024;
  const float* qrow = kq + ((size_t)b * 16 + m) * 1024 + 512;
  float s = 0.f;
#pragma unroll 8
  for (int d = 0; d < 512; d += 4) {
    f32x4 kv = *(const f32x4*)(krow + d);
    f32x4 qv = *(const f32x4*)(qrow + d);
    s += kv[0]*qv[0] + kv[1]*qv[1] + kv[2]*qv[2] + kv[3]*qv[3];
  }
  float mx = s;
  mx = fmaxf(mx, __shfl_xor(mx, 1)); mx = fmaxf(mx, __shfl_xor(mx, 2));
  mx = fmaxf(mx, __shfl_xor(mx, 4)); mx = fmaxf(mx, __shfl_xor(mx, 8));
  float e = __expf(s - mx);
  float sum = e;
  sum += __shfl_xor(sum, 1); sum += __shfl_xor(sum, 2);
  sum += __shfl_xor(sum, 4); sum += __shfl_xor(sum, 8);
  float pv = e / sum;
  float pl[16];
#pragma unroll
  for (int i = 0; i < 16; ++i) pl[i] = __shfl(pv, (lane & 48) + i);
  float* od = Tdash + ((size_t)b * 16 + l) * 1024 + c0;
  unsigned short* ob = Tdbf + ((size_t)b * 16 + l) * 1024 + c0;
#pragma unroll
  for (int h = 0; h < 2; ++h) {
    int c = m * 8 + h * 4;
    f32x4 o = *(const f32x4*)&Ts[l][c];
#pragma unroll
    for (int mm = 0; mm < 16; ++mm) {
      f32x4 tv = *(const f32x4*)&Ts[mm][c];
      o += pl[mm] * tv;
    }
    *(f32x4*)(od + c) = o;
    ushort4v hh; hh[0]=f2bf(o[0]); hh[1]=f2bf(o[1]); hh[2]=f2bf(o[2]); hh[3]=f2bf(o[3]);
    *(ushort4v*)(ob + c) = hh;
  }
}

// ---------------- r[b,l] = q_b . Tk[b,l,:] ----------------
__global__ __launch_bounds__(256) void r_kernel(
    const unsigned short* __restrict__ Tkbf, const float* __restrict__ qb,
    float* __restrict__ r)
{
  int row = blockIdx.x * 4 + (threadIdx.x >> 6);
  int lane = threadIdx.x & 63;
  const unsigned short* p = Tkbf + (size_t)row * CC;
  float s = 0.f;
#pragma unroll
  for (int h = 0; h < 2; ++h) {
    int d0 = lane * 8 + h * 512;
    short8 v = *(const short8*)&p[d0];
#pragma unroll
    for (int jj = 0; jj < 8; ++jj)
      s += bf2f((unsigned short)v[jj]) * qb[d0 + jj];
  }
#pragma unroll
  for (int msk = 32; msk >= 1; msk >>= 1) s += __shfl_xor(s, msk);
  if (lane == 0) r[row] = s;
}

// ---------------- sim partial: Spart[kh][pix][l] = (X @ Gt^T) over K-half ----------------
__global__ __launch_bounds__(256) void sim_part(
    const float* __restrict__ X, const unsigned short* __restrict__ Gt,
    float* __restrict__ Spart)
{
  __shared__ __align__(16) char sp[16384];
  int tid = threadIdx.x, wid = tid >> 6, lane = tid & 63;
  int lr = lane & 15, hi = lane >> 4;
  int ch = blockIdx.x, kh = blockIdx.y, b = blockIdx.z;
  int pix0 = b * 1024 + ch * 64;
  int row = tid >> 2, seg = tid & 3;
  const float* xr = X + (size_t)(pix0 + row) * 1024 + kh * 512 + seg * 32;
  const unsigned short* Wb = Gt + (size_t)b * 16 * 1024 + (size_t)lr * 1024 + kh * 512 + hi * 8;
  int wbyte[4];
#pragma unroll
  for (int u = 0; u < 4; ++u)
    wbyte[u] = row * 256 + (((seg * 64 + u * 16) ^ ((row & 7) << 4)));
  int arow = wid * 16 + lr;
  int rbyte = arow * 256;
  int rx = (arow & 7) << 4;
  f32x4 acc = (f32x4)0.f;
  for (int k0 = 0; k0 < 512; k0 += 128) {
    f32x4 v[8];
#pragma unroll
    for (int i = 0; i < 8; ++i) v[i] = *(const f32x4*)(xr + k0 + i * 4);
    __syncthreads();
#pragma unroll
    for (int u = 0; u < 4; ++u) {
      short8 pk;
      pk[0] = (short)f2bf(v[2*u][0]);   pk[1] = (short)f2bf(v[2*u][1]);
      pk[2] = (short)f2bf(v[2*u][2]);   pk[3] = (short)f2bf(v[2*u][3]);
      pk[4] = (short)f2bf(v[2*u+1][0]); pk[5] = (short)f2bf(v[2*u+1][1]);
      pk[6] = (short)f2bf(v[2*u+1][2]); pk[7] = (short)f2bf(v[2*u+1][3]);
      *(short8*)(sp + wbyte[u]) = pk;
    }
    __syncthreads();
#pragma unroll
    for (int kk = 0; kk < 4; ++kk) {
      short8 af = *(const short8*)(sp + rbyte + (((kk * 64 + hi * 16) ^ rx)));
      short8 bfv = *(const short8*)(Wb + k0 + kk * 32);
      acc = __builtin_amdgcn_mfma_f32_16x16x32_bf16(af, bfv, acc, 0, 0, 0);
    }
  }
  int pixb = pix0 + wid * 16 + hi * 4;
#pragma unroll
  for (int rr = 0; rr < 4; ++rr)
    Spart[((size_t)kh * 32768 + pixb + rr) * 16 + lr] = acc[rr];
}

// ---------------- merge sim partials + softmax over L -> P ----------------
__global__ __launch_bounds__(256) void softmaxP(
    const float* __restrict__ Spart, const float* __restrict__ r,
    float* __restrict__ P)
{
  int tid = threadIdx.x;
  int pix = blockIdx.x * 16 + (tid >> 4);
  int l = tid & 15;
  int b = pix >> 10;
  float s = Spart[(size_t)pix * 16 + l] + Spart[((size_t)32768 + pix) * 16 + l]
          + r[b * 16 + l];
  float mx = s;
  mx = fmaxf(mx, __shfl_xor(mx, 1)); mx = fmaxf(mx, __shfl_xor(mx, 2));
  mx = fmaxf(mx, __shfl_xor(mx, 4)); mx = fmaxf(mx, __shfl_xor(mx, 8));
  float e = __expf(s - mx);
  float sum = e;
  sum += __shfl_xor(sum, 1); sum += __shfl_xor(sum, 2);
  sum += __shfl_xor(sum, 4); sum += __shfl_xor(sum, 8);
  P[(size_t)pix * 16 + l] = e / sum;
}

// ---------------- X_out = X + P @ T_out (32-pixel chunks, grid 1024) ----------------
__global__ __launch_bounds__(256) void out_kernel(
    const float* __restrict__ X, const float* __restrict__ P,
    const float* __restrict__ Tout, float* __restrict__ Xout)
{
  int b = blockIdx.y, ch = blockIdx.x;   // 32 chunks x 32 pixels
  int tid = threadIdx.x;
  int c4 = tid * 4;
  int pb = b * 1024 + ch * 32;
  f32x4 tsr[16];
#pragma unroll
  for (int l = 0; l < 16; ++l)
    tsr[l] = *(const f32x4*)&Tout[((size_t)b * 16 + l) * 1024 + c4];
  __shared__ float Ps[32][16];
  if (tid < 128)
    *(f32x4*)&Ps[tid >> 2][(tid & 3) * 4] =
        *(const f32x4*)&P[((size_t)pb + (tid >> 2)) * 16 + (tid & 3) * 4];
  __syncthreads();
  const float* xp = X + (size_t)pb * 1024 + c4;
  float* op = Xout + (size_t)pb * 1024 + c4;
  for (int n0 = 0; n0 < 32; n0 += 8) {
    f32x4 xv[8];
#pragma unroll
    for (int i = 0; i < 8; ++i) xv[i] = *(const f32x4*)(xp + (size_t)(n0 + i) * 1024);
#pragma unroll
    for (int i = 0; i < 8; ++i) {
      const f32x4* pr = (const f32x4*)&Ps[n0 + i][0];
      f32x4 p0 = pr[0], p1 = pr[1], p2 = pr[2], p3 = pr[3];
      f32x4 o = xv[i];
      o += p0[0]*tsr[0];  o += p0[1]*tsr[1];  o += p0[2]*tsr[2];  o += p0[3]*tsr[3];
      o += p1[0]*tsr[4];  o += p1[1]*tsr[5];  o += p1[2]*tsr[6];  o += p1[3]*tsr[7];
      o += p2[0]*tsr[8];  o += p2[1]*tsr[9];  o += p2[2]*tsr[10]; o += p2[3]*tsr[11];
      o += p3[0]*tsr[12]; o += p3[1]*tsr[13]; o += p3[2]*tsr[14]; o += p3[3]*tsr[15];
      __builtin_nontemporal_store(o, (f32x4*)(op + (size_t)(n0 + i) * 1024));
    }
  }
}

extern "C" void kernel_launch(void* const* d_in, const int* in_sizes, int n_in,
                              void* d_out, int out_size, void* d_ws, size_t ws_size,
                              hipStream_t stream)
{
  const float* X      = (const float*)d_in[0];
  const float* tokW   = (const float*)d_in[2];
  const float* tokB   = (const float*)d_in[3];
  const float* keyW   = (const float*)d_in[4];
  const float* keyB   = (const float*)d_in[5];
  const float* queryW = (const float*)d_in[6];
  const float* queryB = (const float*)d_in[7];
  const float* f1W    = (const float*)d_in[8];
  const float* f1B    = (const float*)d_in[9];
  const float* f2W    = (const float*)d_in[10];
  const float* f2B    = (const float*)d_in[11];
  const float* qW     = (const float*)d_in[12];
  const float* qB     = (const float*)d_in[13];
  const float* kW     = (const float*)d_in[14];
  const float* kB     = (const float*)d_in[15];

  float* Xout = (float*)d_out;
  float* Tout = (float*)d_out + (size_t)BB * NN * CC;

  char* ws = (char*)d_ws;
  size_t off = 0;
  auto alloc_f = [&](size_t n) { float* pp = (float*)(ws + off); off += n * 4; return pp; };
  float* Tbuf   = alloc_f(524288);
  float* kqbuf  = alloc_f(524288);
  float* Tdash  = alloc_f(524288);
  float* Spart  = alloc_f(1048576);   // [2][32768][16]
  float* Pbuf   = alloc_f(524288);    // [32768][16]
  float* rbuf   = alloc_f(1024);
  float* biaskq = alloc_f(1024);
  float* Mloc   = alloc_f(8192);
  float* Sloc   = alloc_f(8192);
  auto alloc_h = [&](size_t n) { unsigned short* pp = (unsigned short*)(ws + off); off += n * 2; return pp; };
  unsigned short* Tp     = alloc_h(8388608);   // [B][16][L][C] bf16
  unsigned short* Tbf    = alloc_h(524288);
  unsigned short* Tdbf   = alloc_h(524288);
  unsigned short* Hbf    = alloc_h(524288);
  unsigned short* Toutbf = alloc_h(524288);
  unsigned short* Tkbf   = alloc_h(524288);
  unsigned short* Gtbf   = alloc_h(524288);
  unsigned short* WkqT   = alloc_h(1048576);
  unsigned short* f1WT   = alloc_h(1048576);
  unsigned short* f2WT   = alloc_h(1048576);
  unsigned short* kWT    = alloc_h(1048576);
  unsigned short* qWbf   = alloc_h(1048576);
  unsigned short* tokWT  = alloc_h(16384);
  (void)ws_size; (void)in_sizes; (void)n_in; (void)out_size;

  wprep<<<dim3(32, 32, 6), dim3(32, 8), 0, stream>>>(keyW, queryW, f1W, f2W, kW, qW,
                                                     tokW, keyB, queryB,
                                                     WkqT, f1WT, f2WT, kWT, qWbf, tokWT, biaskq);
  tok_fused<<<dim3(16, 32), 256, 0, stream>>>(X, tokWT, tokB, Tp, Mloc, Sloc);
  tmerge<<<256, 256, 0, stream>>>(Tp, Mloc, Sloc, Tbuf, Tbf);
  gemm32x32<0,1,0,1,0><<<dim3(16, 32), 256, 0, stream>>>(Tbf, WkqT, biaskq, nullptr, kqbuf, nullptr);
  scores_tdash<<<dim3(8, 32), 256, 0, stream>>>(kqbuf, Tbuf, Tdash, Tdbf);
  gemm32x32<1,1,0,0,1><<<dim3(16, 32), 256, 0, stream>>>(Tdbf, f1WT, f1B, nullptr, nullptr, Hbf);
  gemm32x32<0,1,1,1,1><<<dim3(16, 32), 256, 0, stream>>>(Hbf, f2WT, f2B, Tdash, Tout, Toutbf);
  gemm32x32<0,1,0,0,1><<<dim3(16, 32), 256, 0, stream>>>(Toutbf, kWT, kB, nullptr, nullptr, Tkbf);
  r_kernel<<<128, 256, 0, stream>>>(Tkbf, qB, rbuf);
  gemm32x32<0,0,0,0,1><<<dim3(16, 32), 256, 0, stream>>>(Tkbf, qWbf, nullptr, nullptr, nullptr, Gtbf);
  sim_part<<<dim3(16, 2, 32), 256, 0, stream>>>(X, Gtbf, Spart);
  softmaxP<<<2048, 256, 0, stream>>>(Spart, rbuf, Pbuf);
  out_kernel<<<dim3(32, 32), 256, 0, stream>>>(X, Pbuf, Tout, Xout);
}

// Round 7
// 230.336 us; speedup vs baseline: 1.8345x; 1.7828x over previous
//
#include <hip/hip_runtime.h>
#include <hip/hip_bf16.h>
#include <stdint.h>

#define BB 32
#define NN 1024
#define CC 1024
#define LL 16

typedef __attribute__((ext_vector_type(4))) float f32x4;
typedef __attribute__((ext_vector_type(8))) short short8;
typedef __attribute__((ext_vector_type(4))) unsigned short ushort4v;

__device__ __forceinline__ unsigned short f2bf(float f) {
  union { float f; unsigned u; } v; v.f = f;
  unsigned r = v.u + 0x7FFF + ((v.u >> 16) & 1);
  return (unsigned short)(r >> 16);
}
__device__ __forceinline__ float bf2f(unsigned short h) {
  union { unsigned u; float f; } v; v.u = ((unsigned)h) << 16; return v.f;
}
__device__ __forceinline__ short8 cvt8(f32x4 a, f32x4 b) {
  short8 r;
  r[0] = (short)f2bf(a[0]); r[1] = (short)f2bf(a[1]);
  r[2] = (short)f2bf(a[2]); r[3] = (short)f2bf(a[3]);
  r[4] = (short)f2bf(b[0]); r[5] = (short)f2bf(b[1]);
  r[6] = (short)f2bf(b[2]); r[7] = (short)f2bf(b[3]);
  return r;
}

// ---------------- weight prep: transpose->bf16 (+ tokW^T, bias pack at z=5) ----------------
__global__ __launch_bounds__(256) void wprep(
    const float* __restrict__ keyW, const float* __restrict__ queryW,
    const float* __restrict__ f1W, const float* __restrict__ f2W,
    const float* __restrict__ kW, const float* __restrict__ qW,
    const float* __restrict__ tokW, const float* __restrict__ keyb,
    const float* __restrict__ queryb,
    unsigned short* __restrict__ WkqT, unsigned short* __restrict__ f1WT,
    unsigned short* __restrict__ f2WT, unsigned short* __restrict__ kWT,
    unsigned short* __restrict__ qWbf, unsigned short* __restrict__ tokWT,
    float* __restrict__ biaskq)
{
  int z = blockIdx.z;
  int tx = threadIdx.x, ty = threadIdx.y;
  if (z == 5) {
    int gid = (blockIdx.y * 32 + blockIdx.x) * 256 + ty * 32 + tx;
    if (gid < 16384) {
      int l = gid >> 10, c = gid & 1023;
      tokWT[gid] = f2bf(tokW[c * 16 + l]);
    } else if (gid < 17408) {
      int i = gid - 16384;
      biaskq[i] = (i < 512) ? keyb[i] : queryb[i - 512];
    }
    return;
  }
  if (z == 4) {
#pragma unroll
    for (int i = 0; i < 4; ++i) {
      int row = blockIdx.y * 32 + ty + 8 * i;
      int col = blockIdx.x * 32 + tx;
      qWbf[row * 1024 + col] = f2bf(qW[row * 1024 + col]);
    }
    return;
  }
  __shared__ float tile[32][33];
  int j0 = blockIdx.x * 32, k0 = blockIdx.y * 32;
  const float* src = (z == 1) ? f1W : (z == 2) ? f2W : kW;
#pragma unroll
  for (int i = 0; i < 4; ++i) {
    int k = k0 + ty + 8 * i;
    int j = j0 + tx;
    float v;
    if (z == 0) v = (j < 512) ? keyW[k * 512 + j] : queryW[k * 512 + (j - 512)];
    else        v = src[k * 1024 + j];
    tile[ty + 8 * i][tx] = v;
  }
  __syncthreads();
  unsigned short* dst = (z == 0) ? WkqT : (z == 1) ? f1WT : (z == 2) ? f2WT : kWT;
#pragma unroll
  for (int i = 0; i < 4; ++i) {
    int j = j0 + ty + 8 * i;
    dst[j * 1024 + k0 + tx] = f2bf(tile[tx][ty + 8 * i]);
  }
}

// ---------------- proj: barrier-free direct-fragment MFMA ----------------
// attn[(b*16+l)*1024 + n] = X @ tokW + tokB (transposed logits)
__global__ __launch_bounds__(256) void proj_direct(
    const float* __restrict__ X, const unsigned short* __restrict__ tokWT,
    const float* __restrict__ tokB, float* __restrict__ attn)
{
  int tid = threadIdx.x, wid = tid >> 6, lane = tid & 63;
  int lr = lane & 15, hi = lane >> 4;
  int pix0 = (blockIdx.x * 4 + wid) * 16;
  int b = pix0 >> 10;
  const float* Ar = X + (size_t)(pix0 + lr) * 1024 + hi * 8;
  const unsigned short* Br = tokWT + lr * 1024 + hi * 8;
  f32x4 acc = (f32x4)0.f;
#pragma unroll 4
  for (int k0 = 0; k0 < 1024; k0 += 32) {
    f32x4 x0 = *(const f32x4*)(Ar + k0);
    f32x4 x1 = *(const f32x4*)(Ar + k0 + 4);
    short8 bfrag = *(const short8*)(Br + k0);
    acc = __builtin_amdgcn_mfma_f32_16x16x32_bf16(cvt8(x0, x1), bfrag, acc, 0, 0, 0);
  }
  float bv = tokB[lr];
  int pixb = pix0 + hi * 4;
#pragma unroll
  for (int rr = 0; rr < 4; ++rr)
    attn[((size_t)b * 16 + lr) * 1024 + ((pixb + rr) & 1023)] = acc[rr] + bv;
}

// ---------------- softmax over N (rows of attn [B*L][N]) ----------------
__global__ __launch_bounds__(256) void softmax_n(float* __restrict__ projT) {
  float* row = projT + (size_t)blockIdx.x * NN;
  int t = threadIdx.x;
  f32x4 v = ((f32x4*)row)[t];
  float m = fmaxf(fmaxf(v[0], v[1]), fmaxf(v[2], v[3]));
#pragma unroll
  for (int msk = 32; msk >= 1; msk >>= 1) m = fmaxf(m, __shfl_xor(m, msk));
  __shared__ float redm[4], reds[4];
  if ((t & 63) == 0) redm[t >> 6] = m;
  __syncthreads();
  m = fmaxf(fmaxf(redm[0], redm[1]), fmaxf(redm[2], redm[3]));
  f32x4 e;
  e[0] = __expf(v[0] - m); e[1] = __expf(v[1] - m);
  e[2] = __expf(v[2] - m); e[3] = __expf(v[3] - m);
  float s = e[0] + e[1] + e[2] + e[3];
#pragma unroll
  for (int msk = 32; msk >= 1; msk >>= 1) s += __shfl_xor(s, msk);
  if ((t & 63) == 0) reds[t >> 6] = s;
  __syncthreads();
  s = reds[0] + reds[1] + reds[2] + reds[3];
  float inv = 1.f / s;
  e[0] *= inv; e[1] *= inv; e[2] *= inv; e[3] *= inv;
  ((f32x4*)row)[t] = e;
}

// ---------------- T partials: bf16 [b][ch=16][l][c], chunk = 64 pixels ----------------
__global__ __launch_bounds__(256) void tpart_kernel(
    const float* __restrict__ X, const float* __restrict__ attnT,
    unsigned short* __restrict__ TpartBf)
{
  int b = blockIdx.y, ch = blockIdx.x;   // ch<16
  int n0 = ch * 64;
  __shared__ float att[64][16];
  int tid = threadIdx.x;
  {
    int l = tid >> 4, n4 = (tid & 15) * 4;
    f32x4 a = *(const f32x4*)&attnT[((size_t)b * 16 + l) * 1024 + n0 + n4];
    att[n4 + 0][l] = a[0]; att[n4 + 1][l] = a[1];
    att[n4 + 2][l] = a[2]; att[n4 + 3][l] = a[3];
  }
  __syncthreads();
  f32x4 acc[16];
#pragma unroll
  for (int l = 0; l < 16; ++l) acc[l] = (f32x4)0.f;
  const float* xp = X + ((size_t)b * 1024 + n0) * 1024 + tid * 4;
  for (int nb = 0; nb < 64; nb += 8) {
    f32x4 xv[8];
#pragma unroll
    for (int i = 0; i < 8; ++i) xv[i] = *(const f32x4*)(xp + (size_t)(nb + i) * 1024);
#pragma unroll
    for (int i = 0; i < 8; ++i) {
      const f32x4* ar = (const f32x4*)&att[nb + i][0];
      f32x4 a0 = ar[0], a1 = ar[1], a2 = ar[2], a3 = ar[3];
      f32x4 x0 = xv[i];
      acc[0]  += a0[0]*x0; acc[1]  += a0[1]*x0; acc[2]  += a0[2]*x0; acc[3]  += a0[3]*x0;
      acc[4]  += a1[0]*x0; acc[5]  += a1[1]*x0; acc[6]  += a1[2]*x0; acc[7]  += a1[3]*x0;
      acc[8]  += a2[0]*x0; acc[9]  += a2[1]*x0; acc[10] += a2[2]*x0; acc[11] += a2[3]*x0;
      acc[12] += a3[0]*x0; acc[13] += a3[1]*x0; acc[14] += a3[2]*x0; acc[15] += a3[3]*x0;
    }
  }
  unsigned short* op = TpartBf + (size_t)(b * 16 + ch) * 16 * 1024 + tid * 4;
#pragma unroll
  for (int l = 0; l < 16; ++l) {
    f32x4 s = acc[l];
    ushort4v h; h[0]=f2bf(s[0]); h[1]=f2bf(s[1]); h[2]=f2bf(s[2]); h[3]=f2bf(s[3]);
    *(ushort4v*)(op + (size_t)l * 1024) = h;
  }
}

__global__ void treduce(const unsigned short* __restrict__ TpartBf,
                        float* __restrict__ T, unsigned short* __restrict__ Tbf) {
  int f = blockIdx.x * 256 + threadIdx.x;   // f4 index < 131072
  int b = f >> 12, w = f & 4095;
  f32x4 s = (f32x4)0.f;
#pragma unroll
  for (int ch = 0; ch < 16; ++ch) {
    ushort4v h = ((const ushort4v*)TpartBf)[(size_t)(b * 16 + ch) * 4096 + w];
    s[0] += bf2f(h[0]); s[1] += bf2f(h[1]); s[2] += bf2f(h[2]); s[3] += bf2f(h[3]);
  }
  ((f32x4*)T)[f] = s;
  ushort4v h; h[0]=f2bf(s[0]); h[1]=f2bf(s[1]); h[2]=f2bf(s[2]); h[3]=f2bf(s[3]);
  ((ushort4v*)Tbf)[f] = h;
}

// ---------------- barrier-free NT bf16 GEMM: M=512, Nn=1024, K=1024 ----------------
// grid (32,16): wave handles 16x16 tile, fragments direct from global (L2-hot).
template<int RELU, int HAS_BIAS, int HAS_RES, int STORE_F32, int STORE_BF16>
__global__ __launch_bounds__(256) void gemm_direct(
    const unsigned short* __restrict__ A, const unsigned short* __restrict__ Bm,
    const float* __restrict__ bias, const float* __restrict__ res,
    float* __restrict__ outF, unsigned short* __restrict__ outB)
{
  int tid = threadIdx.x, wid = tid >> 6, lane = tid & 63;
  int lr = lane & 15, hi = lane >> 4;
  int m0 = blockIdx.x * 16;
  int n0 = (blockIdx.y * 4 + wid) * 16;
  const unsigned short* Ap = A + (size_t)(m0 + lr) * 1024 + hi * 8;
  const unsigned short* Bp = Bm + (size_t)(n0 + lr) * 1024 + hi * 8;
  f32x4 acc = (f32x4)0.f;
#pragma unroll 8
  for (int k0 = 0; k0 < 1024; k0 += 32) {
    short8 a = *(const short8*)(Ap + k0);
    short8 b = *(const short8*)(Bp + k0);
    acc = __builtin_amdgcn_mfma_f32_16x16x32_bf16(a, b, acc, 0, 0, 0);
  }
  int row0 = m0 + hi * 4;
  int col = n0 + lr;
  float bv_ = HAS_BIAS ? bias[col] : 0.f;
#pragma unroll
  for (int rr = 0; rr < 4; ++rr) {
    float x = acc[rr] + bv_;
    if (RELU) x = fmaxf(x, 0.f);
    size_t idx = (size_t)(row0 + rr) * 1024 + col;
    if (HAS_RES) x += res[idx];
    if (STORE_F32) outF[idx] = x;
    if (STORE_BF16) outB[idx] = f2bf(x);
  }
}

// ---------------- token self-attn: scores + softmax + T_dash (c-split 8) ----------------
__global__ __launch_bounds__(256) void scores_tdash(
    const float* __restrict__ kq, const float* __restrict__ T,
    float* __restrict__ Tdash, unsigned short* __restrict__ Tdbf)
{
  int cs = blockIdx.x, b = blockIdx.y;
  int c0 = cs * 128;
  __shared__ float Ts[16][128];
  int tid = threadIdx.x, lane = tid & 63;
#pragma unroll
  for (int i = 0; i < 2; ++i) {
    int fi = tid + 256 * i;            // f4 over 512
    int rrow = fi >> 5, c4 = (fi & 31) * 4;
    *(f32x4*)&Ts[rrow][c4] = *(const f32x4*)&T[((size_t)b * 16 + rrow) * 1024 + c0 + c4];
  }
  __syncthreads();
  int l = tid >> 4, m = tid & 15;
  const float* krow = kq + ((size_t)b * 16 + l) * 1024;
  const float* qrow = kq + ((size_t)b * 16 + m) * 1024 + 512;
  float s = 0.f;
#pragma unroll 8
  for (int d = 0; d < 512; d += 4) {
    f32x4 kv = *(const f32x4*)(krow + d);
    f32x4 qv = *(const f32x4*)(qrow + d);
    s += kv[0]*qv[0] + kv[1]*qv[1] + kv[2]*qv[2] + kv[3]*qv[3];
  }
  float mx = s;
  mx = fmaxf(mx, __shfl_xor(mx, 1)); mx = fmaxf(mx, __shfl_xor(mx, 2));
  mx = fmaxf(mx, __shfl_xor(mx, 4)); mx = fmaxf(mx, __shfl_xor(mx, 8));
  float e = __expf(s - mx);
  float sum = e;
  sum += __shfl_xor(sum, 1); sum += __shfl_xor(sum, 2);
  sum += __shfl_xor(sum, 4); sum += __shfl_xor(sum, 8);
  float pv = e / sum;
  float pl[16];
#pragma unroll
  for (int i = 0; i < 16; ++i) pl[i] = __shfl(pv, (lane & 48) + i);
  float* od = Tdash + ((size_t)b * 16 + l) * 1024 + c0;
  unsigned short* ob = Tdbf + ((size_t)b * 16 + l) * 1024 + c0;
#pragma unroll
  for (int h = 0; h < 2; ++h) {
    int c = m * 8 + h * 4;
    f32x4 o = *(const f32x4*)&Ts[l][c];
#pragma unroll
    for (int mm = 0; mm < 16; ++mm) {
      f32x4 tv = *(const f32x4*)&Ts[mm][c];
      o += pl[mm] * tv;
    }
    *(f32x4*)(od + c) = o;
    ushort4v hh; hh[0]=f2bf(o[0]); hh[1]=f2bf(o[1]); hh[2]=f2bf(o[2]); hh[3]=f2bf(o[3]);
    *(ushort4v*)(ob + c) = hh;
  }
}

// ---------------- r[b,l] = q_b . Tk[b,l,:] ----------------
__global__ __launch_bounds__(256) void r_kernel(
    const unsigned short* __restrict__ Tkbf, const float* __restrict__ qb,
    float* __restrict__ r)
{
  int row = blockIdx.x * 4 + (threadIdx.x >> 6);
  int lane = threadIdx.x & 63;
  const unsigned short* p = Tkbf + (size_t)row * CC;
  float s = 0.f;
#pragma unroll
  for (int h = 0; h < 2; ++h) {
    int d0 = lane * 8 + h * 512;
    short8 v = *(const short8*)&p[d0];
#pragma unroll
    for (int jj = 0; jj < 8; ++jj)
      s += bf2f((unsigned short)v[jj]) * qb[d0 + jj];
  }
#pragma unroll
  for (int msk = 32; msk >= 1; msk >>= 1) s += __shfl_xor(s, msk);
  if (lane == 0) r[row] = s;
}

// ---------------- fused sim + out: direct-fragment MFMA, P in LDS, X_out = X + P@T_out ----------------
__global__ __launch_bounds__(256) void sim_out_kernel(
    const float* __restrict__ X, const unsigned short* __restrict__ Gt,
    const float* __restrict__ rbias, const float* __restrict__ Tout,
    float* __restrict__ Xout)
{
  __shared__ float Ps[64][16];
  int tid = threadIdx.x, wid = tid >> 6, lane = tid & 63;
  int lr = lane & 15, hi = lane >> 4;
  int b = blockIdx.y;
  int pix0b = b * 1024 + blockIdx.x * 64;
  int pix0 = pix0b + wid * 16;
  const float* Ar = X + (size_t)(pix0 + lr) * 1024 + hi * 8;
  const unsigned short* Br = Gt + (size_t)b * 16384 + lr * 1024 + hi * 8;
  f32x4 acc = (f32x4)0.f;
#pragma unroll 4
  for (int k0 = 0; k0 < 1024; k0 += 32) {
    f32x4 x0 = *(const f32x4*)(Ar + k0);
    f32x4 x1 = *(const f32x4*)(Ar + k0 + 4);
    short8 bfrag = *(const short8*)(Br + k0);
    acc = __builtin_amdgcn_mfma_f32_16x16x32_bf16(cvt8(x0, x1), bfrag, acc, 0, 0, 0);
  }
  // in-register softmax over l (16-lane groups), P -> LDS
  float bv = rbias[b * 16 + lr];
  int prow = wid * 16 + hi * 4;
#pragma unroll
  for (int rr = 0; rr < 4; ++rr) {
    float vv = acc[rr] + bv;
    float mx = vv;
    mx = fmaxf(mx, __shfl_xor(mx, 1)); mx = fmaxf(mx, __shfl_xor(mx, 2));
    mx = fmaxf(mx, __shfl_xor(mx, 4)); mx = fmaxf(mx, __shfl_xor(mx, 8));
    float e = __expf(vv - mx);
    float ss = e;
    ss += __shfl_xor(ss, 1); ss += __shfl_xor(ss, 2);
    ss += __shfl_xor(ss, 4); ss += __shfl_xor(ss, 8);
    Ps[prow + rr][lr] = e / ss;
  }
  __syncthreads();
  // phase 2: X_out = X + P @ T_out, T_out column-slice in registers
  int c4 = tid * 4;
  f32x4 tsr[16];
#pragma unroll
  for (int l = 0; l < 16; ++l)
    tsr[l] = *(const f32x4*)&Tout[((size_t)b * 16 + l) * 1024 + c4];
  const float* xp = X + (size_t)pix0b * 1024 + c4;
  float* op = Xout + (size_t)pix0b * 1024 + c4;
#pragma unroll 2
  for (int n = 0; n < 64; ++n) {
    f32x4 xv = *(const f32x4*)(xp + (size_t)n * 1024);
    const f32x4* pr = (const f32x4*)&Ps[n][0];
    f32x4 p0 = pr[0], p1 = pr[1], p2 = pr[2], p3 = pr[3];
    f32x4 o = xv;
    o += p0[0]*tsr[0];  o += p0[1]*tsr[1];  o += p0[2]*tsr[2];  o += p0[3]*tsr[3];
    o += p1[0]*tsr[4];  o += p1[1]*tsr[5];  o += p1[2]*tsr[6];  o += p1[3]*tsr[7];
    o += p2[0]*tsr[8];  o += p2[1]*tsr[9];  o += p2[2]*tsr[10]; o += p2[3]*tsr[11];
    o += p3[0]*tsr[12]; o += p3[1]*tsr[13]; o += p3[2]*tsr[14]; o += p3[3]*tsr[15];
    __builtin_nontemporal_store(o, (f32x4*)(op + (size_t)n * 1024));
  }
}

extern "C" void kernel_launch(void* const* d_in, const int* in_sizes, int n_in,
                              void* d_out, int out_size, void* d_ws, size_t ws_size,
                              hipStream_t stream)
{
  const float* X      = (const float*)d_in[0];
  const float* tokW   = (const float*)d_in[2];
  const float* tokB   = (const float*)d_in[3];
  const float* keyW   = (const float*)d_in[4];
  const float* keyB   = (const float*)d_in[5];
  const float* queryW = (const float*)d_in[6];
  const float* queryB = (const float*)d_in[7];
  const float* f1W    = (const float*)d_in[8];
  const float* f1B    = (const float*)d_in[9];
  const float* f2W    = (const float*)d_in[10];
  const float* f2B    = (const float*)d_in[11];
  const float* qW     = (const float*)d_in[12];
  const float* qB     = (const float*)d_in[13];
  const float* kW     = (const float*)d_in[14];
  const float* kB     = (const float*)d_in[15];

  float* Xout = (float*)d_out;
  float* Tout = (float*)d_out + (size_t)BB * NN * CC;

  char* ws = (char*)d_ws;
  size_t off = 0;
  auto alloc_f = [&](size_t n) { float* pp = (float*)(ws + off); off += n * 4; return pp; };
  float* attn   = alloc_f(524288);    // [B*L][N] logits -> softmaxed in place
  float* Tbuf   = alloc_f(524288);
  float* kqbuf  = alloc_f(524288);
  float* Tdash  = alloc_f(524288);
  float* rbuf   = alloc_f(1024);
  float* biaskq = alloc_f(1024);
  auto alloc_h = [&](size_t n) { unsigned short* pp = (unsigned short*)(ws + off); off += n * 2; return pp; };
  unsigned short* TpartBf = alloc_h(8388608);  // [B][16][L][C] bf16
  unsigned short* Tbf    = alloc_h(524288);
  unsigned short* Tdbf   = alloc_h(524288);
  unsigned short* Hbf    = alloc_h(524288);
  unsigned short* Toutbf = alloc_h(524288);
  unsigned short* Tkbf   = alloc_h(524288);
  unsigned short* Gtbf   = alloc_h(524288);
  unsigned short* WkqT   = alloc_h(1048576);
  unsigned short* f1WT   = alloc_h(1048576);
  unsigned short* f2WT   = alloc_h(1048576);
  unsigned short* kWT    = alloc_h(1048576);
  unsigned short* qWbf   = alloc_h(1048576);
  unsigned short* tokWT  = alloc_h(16384);
  (void)ws_size; (void)in_sizes; (void)n_in; (void)out_size;

  wprep<<<dim3(32, 32, 6), dim3(32, 8), 0, stream>>>(keyW, queryW, f1W, f2W, kW, qW,
                                                     tokW, keyB, queryB,
                                                     WkqT, f1WT, f2WT, kWT, qWbf, tokWT, biaskq);
  proj_direct<<<512, 256, 0, stream>>>(X, tokWT, tokB, attn);
  softmax_n<<<512, 256, 0, stream>>>(attn);
  tpart_kernel<<<dim3(16, 32), 256, 0, stream>>>(X, attn, TpartBf);
  treduce<<<512, 256, 0, stream>>>(TpartBf, Tbuf, Tbf);
  gemm_direct<0,1,0,1,0><<<dim3(32, 16), 256, 0, stream>>>(Tbf, WkqT, biaskq, nullptr, kqbuf, nullptr);
  scores_tdash<<<dim3(8, 32), 256, 0, stream>>>(kqbuf, Tbuf, Tdash, Tdbf);
  gemm_direct<1,1,0,0,1><<<dim3(32, 16), 256, 0, stream>>>(Tdbf, f1WT, f1B, nullptr, nullptr, Hbf);
  gemm_direct<0,1,1,1,1><<<dim3(32, 16), 256, 0, stream>>>(Hbf, f2WT, f2B, Tdash, Tout, Toutbf);
  gemm_direct<0,1,0,0,1><<<dim3(32, 16), 256, 0, stream>>>(Toutbf, kWT, kB, nullptr, nullptr, Tkbf);
  r_kernel<<<128, 256, 0, stream>>>(Tkbf, qB, rbuf);
  gemm_direct<0,0,0,0,1><<<dim3(32, 16), 256, 0, stream>>>(Tkbf, qWbf, nullptr, nullptr, nullptr, Gtbf);
  sim_out_kernel<<<dim3(16, 32), 256, 0, stream>>>(X, Gtbf, rbuf, Tout, Xout);
}

// Round 8
// 178.163 us; speedup vs baseline: 2.3717x; 1.2928x over previous
//
#include <hip/hip_runtime.h>
#include <hip/hip_bf16.h>
#include <stdint.h>

#define BB 32
#define NN 1024
#define CC 1024
#define LL 16

typedef __attribute__((ext_vector_type(4))) float f32x4;
typedef __attribute__((ext_vector_type(8))) short short8;
typedef __attribute__((ext_vector_type(4))) unsigned short ushort4v;

__device__ __forceinline__ unsigned short f2bf(float f) {
  union { float f; unsigned u; } v; v.f = f;
  unsigned r = v.u + 0x7FFF + ((v.u >> 16) & 1);
  return (unsigned short)(r >> 16);
}
__device__ __forceinline__ float bf2f(unsigned short h) {
  union { unsigned u; float f; } v; v.u = ((unsigned)h) << 16; return v.f;
}
__device__ __forceinline__ short8 cvt8(f32x4 a, f32x4 b) {
  short8 r;
  r[0] = (short)f2bf(a[0]); r[1] = (short)f2bf(a[1]);
  r[2] = (short)f2bf(a[2]); r[3] = (short)f2bf(a[3]);
  r[4] = (short)f2bf(b[0]); r[5] = (short)f2bf(b[1]);
  r[6] = (short)f2bf(b[2]); r[7] = (short)f2bf(b[3]);
  return r;
}

// ---------------- weight prep: transpose->bf16 (+ tokW^T, bias pack at z=5) ----------------
__global__ __launch_bounds__(256) void wprep(
    const float* __restrict__ keyW, const float* __restrict__ queryW,
    const float* __restrict__ f1W, const float* __restrict__ f2W,
    const float* __restrict__ kW, const float* __restrict__ qW,
    const float* __restrict__ tokW, const float* __restrict__ keyb,
    const float* __restrict__ queryb,
    unsigned short* __restrict__ WkqT, unsigned short* __restrict__ f1WT,
    unsigned short* __restrict__ f2WT, unsigned short* __restrict__ kWT,
    unsigned short* __restrict__ qWbf, unsigned short* __restrict__ tokWT,
    float* __restrict__ biaskq)
{
  int z = blockIdx.z;
  int tx = threadIdx.x, ty = threadIdx.y;
  if (z == 5) {
    int gid = (blockIdx.y * 32 + blockIdx.x) * 256 + ty * 32 + tx;
    if (gid < 16384) {
      int l = gid >> 10, c = gid & 1023;
      tokWT[gid] = f2bf(tokW[c * 16 + l]);
    } else if (gid < 17408) {
      int i = gid - 16384;
      biaskq[i] = (i < 512) ? keyb[i] : queryb[i - 512];
    }
    return;
  }
  if (z == 4) {
#pragma unroll
    for (int i = 0; i < 4; ++i) {
      int row = blockIdx.y * 32 + ty + 8 * i;
      int col = blockIdx.x * 32 + tx;
      qWbf[row * 1024 + col] = f2bf(qW[row * 1024 + col]);
    }
    return;
  }
  __shared__ float tile[32][33];
  int j0 = blockIdx.x * 32, k0 = blockIdx.y * 32;
  const float* src = (z == 1) ? f1W : (z == 2) ? f2W : kW;
#pragma unroll
  for (int i = 0; i < 4; ++i) {
    int k = k0 + ty + 8 * i;
    int j = j0 + tx;
    float v;
    if (z == 0) v = (j < 512) ? keyW[k * 512 + j] : queryW[k * 512 + (j - 512)];
    else        v = src[k * 1024 + j];
    tile[ty + 8 * i][tx] = v;
  }
  __syncthreads();
  unsigned short* dst = (z == 0) ? WkqT : (z == 1) ? f1WT : (z == 2) ? f2WT : kWT;
#pragma unroll
  for (int i = 0; i < 4; ++i) {
    int j = j0 + ty + 8 * i;
    dst[j * 1024 + k0 + tx] = f2bf(tile[tx][ty + 8 * i]);
  }
}

// ---------------- fused tokenizer: direct-frag proj MFMA + chunk softmax + partial T ----------------
// block = (ch<16, b): 64 pixels. One X HBM pass; outer-product phase re-reads chunk from L2.
__global__ __launch_bounds__(256) void tok_fused(
    const float* __restrict__ X, const unsigned short* __restrict__ tokWT,
    const float* __restrict__ tokB, unsigned short* __restrict__ Tp,
    float* __restrict__ Mloc, float* __restrict__ Sloc)
{
  __shared__ float E[64][16];
  __shared__ float redm[4][16];
  __shared__ float reds[4][16];
  int tid = threadIdx.x, wid = tid >> 6, lane = tid & 63;
  int lr = lane & 15, hi = lane >> 4;
  int b = blockIdx.y, ch = blockIdx.x;
  int pix0 = b * 1024 + ch * 64;
  // phase 1: S = X @ tokW^T via direct-fragment MFMA (wave handles 16 rows)
  const float* Ar = X + (size_t)(pix0 + wid * 16 + lr) * 1024 + hi * 8;
  const unsigned short* Br = tokWT + lr * 1024 + hi * 8;
  f32x4 acc = (f32x4)0.f;
#pragma unroll 4
  for (int k0 = 0; k0 < 1024; k0 += 32) {
    f32x4 x0 = *(const f32x4*)(Ar + k0);
    f32x4 x1 = *(const f32x4*)(Ar + k0 + 4);
    short8 bfrag = *(const short8*)(Br + k0);
    acc = __builtin_amdgcn_mfma_f32_16x16x32_bf16(cvt8(x0, x1), bfrag, acc, 0, 0, 0);
  }
  // chunk-local softmax partials per column l=lr; lane holds rows wid*16+hi*4+rr
  float tb = tokB[lr];
  float sv[4];
#pragma unroll
  for (int rr = 0; rr < 4; ++rr) sv[rr] = acc[rr] + tb;
  float pm = fmaxf(fmaxf(sv[0], sv[1]), fmaxf(sv[2], sv[3]));
  pm = fmaxf(pm, __shfl_xor(pm, 16));
  pm = fmaxf(pm, __shfl_xor(pm, 32));
  if (hi == 0) redm[wid][lr] = pm;
  __syncthreads();
  float m = fmaxf(fmaxf(redm[0][lr], redm[1][lr]), fmaxf(redm[2][lr], redm[3][lr]));
  float ev[4]; float ps = 0.f;
#pragma unroll
  for (int i = 0; i < 4; ++i) { ev[i] = __expf(sv[i] - m); ps += ev[i]; }
  ps += __shfl_xor(ps, 16); ps += __shfl_xor(ps, 32);
  if (hi == 0) reds[wid][lr] = ps;
#pragma unroll
  for (int rr = 0; rr < 4; ++rr)
    E[wid * 16 + hi * 4 + rr][lr] = ev[rr];
  __syncthreads();
  if (tid < 16) {
    float sl = reds[0][tid] + reds[1][tid] + reds[2][tid] + reds[3][tid];
    Mloc[(b * 16 + ch) * 16 + tid] = m;
    Sloc[(b * 16 + ch) * 16 + tid] = sl;
  }
  // phase 2: partial T[l][c] = sum_n E[n][l] * X[n][c]  (chunk L2-hot)
  f32x4 a16[16];
#pragma unroll
  for (int l = 0; l < 16; ++l) a16[l] = (f32x4)0.f;
  const float* xp = X + (size_t)pix0 * 1024 + tid * 4;
  for (int n0 = 0; n0 < 64; n0 += 8) {
    f32x4 xv[8];
#pragma unroll
    for (int i = 0; i < 8; ++i) xv[i] = *(const f32x4*)(xp + (size_t)(n0 + i) * 1024);
#pragma unroll
    for (int i = 0; i < 8; ++i) {
      const f32x4* ar = (const f32x4*)&E[n0 + i][0];
      f32x4 a0 = ar[0], a1 = ar[1], a2 = ar[2], a3 = ar[3];
      f32x4 x0 = xv[i];
      a16[0]  += a0[0]*x0; a16[1]  += a0[1]*x0; a16[2]  += a0[2]*x0; a16[3]  += a0[3]*x0;
      a16[4]  += a1[0]*x0; a16[5]  += a1[1]*x0; a16[6]  += a1[2]*x0; a16[7]  += a1[3]*x0;
      a16[8]  += a2[0]*x0; a16[9]  += a2[1]*x0; a16[10] += a2[2]*x0; a16[11] += a2[3]*x0;
      a16[12] += a3[0]*x0; a16[13] += a3[1]*x0; a16[14] += a3[2]*x0; a16[15] += a3[3]*x0;
    }
  }
  unsigned short* op = Tp + ((size_t)(b * 16 + ch) * 16) * 1024 + tid * 4;
#pragma unroll
  for (int l = 0; l < 16; ++l) {
    f32x4 s = a16[l];
    ushort4v h; h[0]=f2bf(s[0]); h[1]=f2bf(s[1]); h[2]=f2bf(s[2]); h[3]=f2bf(s[3]);
    *(ushort4v*)(op + (size_t)l * 1024) = h;
  }
}

// ---------------- merge 16 chunk partials with online-softmax rescale ----------------
__global__ __launch_bounds__(256) void tmerge(
    const unsigned short* __restrict__ Tp, const float* __restrict__ Mloc,
    const float* __restrict__ Sloc, float* __restrict__ T,
    unsigned short* __restrict__ Tbf)
{
  int tid = threadIdx.x;
  int g = blockIdx.x * 2 + (tid >> 7);    // token row in [0,512)
  int b = g >> 4, l = g & 15;
  int j = tid & 127;
  float M = -1e30f;
#pragma unroll
  for (int ch = 0; ch < 16; ++ch) M = fmaxf(M, Mloc[(b * 16 + ch) * 16 + l]);
  float w[16]; float denom = 0.f;
#pragma unroll
  for (int ch = 0; ch < 16; ++ch) {
    w[ch] = __expf(Mloc[(b * 16 + ch) * 16 + l] - M);
    denom += w[ch] * Sloc[(b * 16 + ch) * 16 + l];
  }
  float inv = 1.f / denom;
  float o[8];
#pragma unroll
  for (int t = 0; t < 8; ++t) o[t] = 0.f;
#pragma unroll
  for (int ch = 0; ch < 16; ++ch) {
    const unsigned short* p = Tp + ((size_t)((b * 16 + ch) * 16 + l)) * 1024 + j * 8;
    short8 v = *(const short8*)p;
    float wc = w[ch];
#pragma unroll
    for (int t = 0; t < 8; ++t) o[t] += wc * bf2f((unsigned short)v[t]);
  }
  f32x4 o0, o1; short8 hb;
#pragma unroll
  for (int t = 0; t < 4; ++t) {
    float x0 = o[t] * inv, x1 = o[4 + t] * inv;
    o0[t] = x0; o1[t] = x1;
    hb[t] = (short)f2bf(x0); hb[4 + t] = (short)f2bf(x1);
  }
  *(f32x4*)(T + (size_t)g * 1024 + j * 8) = o0;
  *(f32x4*)(T + (size_t)g * 1024 + j * 8 + 4) = o1;
  *(short8*)(Tbf + (size_t)g * 1024 + j * 8) = hb;
}

// ---------------- NT bf16 GEMM, M=512, Nn=1024, K=1024, 32x64 tiles ----------------
template<int RELU, int HAS_BIAS, int HAS_RES, int STORE_F32, int STORE_BF16>
__global__ __launch_bounds__(256) void gemm32x64(
    const unsigned short* __restrict__ A, const unsigned short* __restrict__ Bm,
    const float* __restrict__ bias, const float* __restrict__ res,
    float* __restrict__ outF, unsigned short* __restrict__ outB)
{
  const int K = 1024;
  __shared__ __align__(16) char sh[12288];   // As 4KB | Bs 8KB, XOR-swizzled rows of 128B
  char* Asp = sh;
  char* Bsp = sh + 4096;
  int tid = threadIdx.x, wid = tid >> 6, lane = tid & 63;
  int lr = lane & 15, hi = lane >> 4;
  int m0 = blockIdx.x * 32, n0 = blockIdx.y * 64;
  int arow = tid >> 3, acol = (tid & 7) * 8;   // A stage: 32x64
  int brow = tid >> 2, bcol = (tid & 3) * 16;  // B stage: 64x64
  const unsigned short* Ap = A + (size_t)(m0 + arow) * K + acol;
  const unsigned short* Bp = Bm + (size_t)(n0 + brow) * K + bcol;
  int aw  = arow * 128 + (((acol * 2) ^ ((arow & 7) << 4)));
  int bw0 = brow * 128 + (((bcol * 2) ^ ((brow & 7) << 4)));
  int bw1 = brow * 128 + ((((bcol * 2) + 16) ^ ((brow & 7) << 4)));
  short8 aR[2]; short8 bR[2][2];
  aR[0]    = *(const short8*)(Ap);
  bR[0][0] = *(const short8*)(Bp);
  bR[0][1] = *(const short8*)(Bp + 8);
  aR[1]    = *(const short8*)(Ap + 64);
  bR[1][0] = *(const short8*)(Bp + 64);
  bR[1][1] = *(const short8*)(Bp + 72);
  f32x4 acc[2];
  acc[0] = (f32x4)0.f; acc[1] = (f32x4)0.f;
  int wm = (wid >> 1) * 16, wn = (wid & 1) * 32;
  int arb = (wm + lr) * 128, arx = ((wm + lr) & 7) << 4;
  for (int s = 0; s < 16; ++s) {
    __syncthreads();
    *(short8*)(Asp + aw)  = aR[s & 1];
    *(short8*)(Bsp + bw0) = bR[s & 1][0];
    *(short8*)(Bsp + bw1) = bR[s & 1][1];
    __syncthreads();
    if (s + 2 < 16) {
      int k0 = (s + 2) * 64;
      aR[s & 1]    = *(const short8*)(Ap + k0);
      bR[s & 1][0] = *(const short8*)(Bp + k0);
      bR[s & 1][1] = *(const short8*)(Bp + k0 + 8);
    }
#pragma unroll
    for (int kk = 0; kk < 2; ++kk) {
      short8 af = *(const short8*)(Asp + arb + (((kk * 64 + hi * 16) ^ arx)));
#pragma unroll
      for (int sn = 0; sn < 2; ++sn) {
        int br = wn + sn * 16 + lr;
        short8 bf = *(const short8*)(Bsp + br * 128 + (((kk * 64 + hi * 16) ^ ((br & 7) << 4))));
        acc[sn] = __builtin_amdgcn_mfma_f32_16x16x32_bf16(af, bf, acc[sn], 0, 0, 0);
      }
    }
  }
  int row0 = m0 + wm + hi * 4;
#pragma unroll
  for (int sn = 0; sn < 2; ++sn) {
    int col = n0 + wn + sn * 16 + lr;
    float bv_ = HAS_BIAS ? bias[col] : 0.f;
#pragma unroll
    for (int rr = 0; rr < 4; ++rr) {
      float x = acc[sn][rr] + bv_;
      if (RELU) x = fmaxf(x, 0.f);
      size_t idx = (size_t)(row0 + rr) * 1024 + col;
      if (HAS_RES) x += res[idx];
      if (STORE_F32) outF[idx] = x;
      if (STORE_BF16) outB[idx] = f2bf(x);
    }
  }
}

// ---------------- token self-attn: scores + softmax + T_dash (c-split 8) ----------------
__global__ __launch_bounds__(256) void scores_tdash(
    const float* __restrict__ kq, const float* __restrict__ T,
    float* __restrict__ Tdash, unsigned short* __restrict__ Tdbf)
{
  int cs = blockIdx.x, b = blockIdx.y;
  int c0 = cs * 128;
  __shared__ float Ts[16][128];
  int tid = threadIdx.x, lane = tid & 63;
#pragma unroll
  for (int i = 0; i < 2; ++i) {
    int fi = tid + 256 * i;            // f4 over 512
    int rrow = fi >> 5, c4 = (fi & 31) * 4;
    *(f32x4*)&Ts[rrow][c4] = *(const f32x4*)&T[((size_t)b * 16 + rrow) * 1024 + c0 + c4];
  }
  __syncthreads();
  int l = tid >> 4, m = tid & 15;
  const float* krow = kq + ((size_t)b * 16 + l) * 1024;
  const float* qrow = kq + ((size_t)b * 16 + m) * 1024 + 512;
  float s = 0.f;
#pragma unroll 8
  for (int d = 0; d < 512; d += 4) {
    f32x4 kv = *(const f32x4*)(krow + d);
    f32x4 qv = *(const f32x4*)(qrow + d);
    s += kv[0]*qv[0] + kv[1]*qv[1] + kv[2]*qv[2] + kv[3]*qv[3];
  }
  float mx = s;
  mx = fmaxf(mx, __shfl_xor(mx, 1)); mx = fmaxf(mx, __shfl_xor(mx, 2));
  mx = fmaxf(mx, __shfl_xor(mx, 4)); mx = fmaxf(mx, __shfl_xor(mx, 8));
  float e = __expf(s - mx);
  float sum = e;
  sum += __shfl_xor(sum, 1); sum += __shfl_xor(sum, 2);
  sum += __shfl_xor(sum, 4); sum += __shfl_xor(sum, 8);
  float pv = e / sum;
  float pl[16];
#pragma unroll
  for (int i = 0; i < 16; ++i) pl[i] = __shfl(pv, (lane & 48) + i);
  float* od = Tdash + ((size_t)b * 16 + l) * 1024 + c0;
  unsigned short* ob = Tdbf + ((size_t)b * 16 + l) * 1024 + c0;
#pragma unroll
  for (int h = 0; h < 2; ++h) {
    int c = m * 8 + h * 4;
    f32x4 o = *(const f32x4*)&Ts[l][c];
#pragma unroll
    for (int mm = 0; mm < 16; ++mm) {
      f32x4 tv = *(const f32x4*)&Ts[mm][c];
      o += pl[mm] * tv;
    }
    *(f32x4*)(od + c) = o;
    ushort4v hh; hh[0]=f2bf(o[0]); hh[1]=f2bf(o[1]); hh[2]=f2bf(o[2]); hh[3]=f2bf(o[3]);
    *(ushort4v*)(ob + c) = hh;
  }
}

// ---------------- r[b,l] = q_b . Tk[b,l,:] ----------------
__global__ __launch_bounds__(256) void r_kernel(
    const unsigned short* __restrict__ Tkbf, const float* __restrict__ qb,
    float* __restrict__ r)
{
  int row = blockIdx.x * 4 + (threadIdx.x >> 6);
  int lane = threadIdx.x & 63;
  const unsigned short* p = Tkbf + (size_t)row * CC;
  float s = 0.f;
#pragma unroll
  for (int h = 0; h < 2; ++h) {
    int d0 = lane * 8 + h * 512;
    short8 v = *(const short8*)&p[d0];
#pragma unroll
    for (int jj = 0; jj < 8; ++jj)
      s += bf2f((unsigned short)v[jj]) * qb[d0 + jj];
  }
#pragma unroll
  for (int msk = 32; msk >= 1; msk >>= 1) s += __shfl_xor(s, msk);
  if (lane == 0) r[row] = s;
}

// ---------------- fused sim + out: P in LDS, X_out = X + P @ T_out ----------------
__global__ __launch_bounds__(256) void sim_out_kernel(
    const float* __restrict__ X, const unsigned short* __restrict__ Gt,
    const float* __restrict__ rbias, const float* __restrict__ Tout,
    float* __restrict__ Xout)
{
  __shared__ __align__(16) char sp[16384];
  __shared__ float Ps[64][16];
  int tid = threadIdx.x, wid = tid >> 6, lane = tid & 63;
  int lr = lane & 15, hi = lane >> 4;
  int pix0 = blockIdx.x * 64 + blockIdx.y * 1024;
  int b = blockIdx.y;
  int row = tid >> 2, seg = tid & 3;
  const float* xr = X + (size_t)(pix0 + row) * 1024 + seg * 32;
  const unsigned short* Wb = Gt + (size_t)b * 16 * 1024 + (size_t)lr * 1024 + hi * 8;
  int wbyte[4];
#pragma unroll
  for (int u = 0; u < 4; ++u)
    wbyte[u] = row * 256 + (((seg * 64 + u * 16) ^ ((row & 7) << 4)));
  int arow = wid * 16 + lr;
  int rbyte = arow * 256;
  int rx = (arow & 7) << 4;
  f32x4 acc = (f32x4)0.f;
  for (int k0 = 0; k0 < 1024; k0 += 128) {
    f32x4 v[8];
#pragma unroll
    for (int i = 0; i < 8; ++i) v[i] = *(const f32x4*)(xr + k0 + i * 4);
    __syncthreads();
#pragma unroll
    for (int u = 0; u < 4; ++u) {
      short8 pk;
      pk[0] = (short)f2bf(v[2*u][0]);   pk[1] = (short)f2bf(v[2*u][1]);
      pk[2] = (short)f2bf(v[2*u][2]);   pk[3] = (short)f2bf(v[2*u][3]);
      pk[4] = (short)f2bf(v[2*u+1][0]); pk[5] = (short)f2bf(v[2*u+1][1]);
      pk[6] = (short)f2bf(v[2*u+1][2]); pk[7] = (short)f2bf(v[2*u+1][3]);
      *(short8*)(sp + wbyte[u]) = pk;
    }
    __syncthreads();
#pragma unroll
    for (int kk = 0; kk < 4; ++kk) {
      short8 af = *(const short8*)(sp + rbyte + (((kk * 64 + hi * 16) ^ rx)));
      short8 bf = *(const short8*)(Wb + k0 + kk * 32);
      acc = __builtin_amdgcn_mfma_f32_16x16x32_bf16(af, bf, acc, 0, 0, 0);
    }
  }
  // in-register softmax over l (16-lane groups), P -> LDS
  float bv = rbias[b * 16 + lr];
  int prow = wid * 16 + hi * 4;
#pragma unroll
  for (int rr = 0; rr < 4; ++rr) {
    float vv = acc[rr] + bv;
    float mx = vv;
    mx = fmaxf(mx, __shfl_xor(mx, 1)); mx = fmaxf(mx, __shfl_xor(mx, 2));
    mx = fmaxf(mx, __shfl_xor(mx, 4)); mx = fmaxf(mx, __shfl_xor(mx, 8));
    float e = __expf(vv - mx);
    float ss = e;
    ss += __shfl_xor(ss, 1); ss += __shfl_xor(ss, 2);
    ss += __shfl_xor(ss, 4); ss += __shfl_xor(ss, 8);
    Ps[prow + rr][lr] = e / ss;
  }
  __syncthreads();
  // phase 2: X_out = X + P @ T_out, T_out column-slice in registers
  int c4 = tid * 4;
  f32x4 tsr[16];
#pragma unroll
  for (int l = 0; l < 16; ++l)
    tsr[l] = *(const f32x4*)&Tout[((size_t)b * 16 + l) * 1024 + c4];
  const float* xp = X + (size_t)pix0 * 1024 + c4;
  float* op = Xout + (size_t)pix0 * 1024 + c4;
#pragma unroll 2
  for (int n = 0; n < 64; ++n) {
    f32x4 xv = *(const f32x4*)(xp + (size_t)n * 1024);
    const f32x4* pr = (const f32x4*)&Ps[n][0];
    f32x4 p0 = pr[0], p1 = pr[1], p2 = pr[2], p3 = pr[3];
    f32x4 o = xv;
    o += p0[0]*tsr[0];  o += p0[1]*tsr[1];  o += p0[2]*tsr[2];  o += p0[3]*tsr[3];
    o += p1[0]*tsr[4];  o += p1[1]*tsr[5];  o += p1[2]*tsr[6];  o += p1[3]*tsr[7];
    o += p2[0]*tsr[8];  o += p2[1]*tsr[9];  o += p2[2]*tsr[10]; o += p2[3]*tsr[11];
    o += p3[0]*tsr[12]; o += p3[1]*tsr[13]; o += p3[2]*tsr[14]; o += p3[3]*tsr[15];
    __builtin_nontemporal_store(o, (f32x4*)(op + (size_t)n * 1024));
  }
}

extern "C" void kernel_launch(void* const* d_in, const int* in_sizes, int n_in,
                              void* d_out, int out_size, void* d_ws, size_t ws_size,
                              hipStream_t stream)
{
  const float* X      = (const float*)d_in[0];
  const float* tokW   = (const float*)d_in[2];
  const float* tokB   = (const float*)d_in[3];
  const float* keyW   = (const float*)d_in[4];
  const float* keyB   = (const float*)d_in[5];
  const float* queryW = (const float*)d_in[6];
  const float* queryB = (const float*)d_in[7];
  const float* f1W    = (const float*)d_in[8];
  const float* f1B    = (const float*)d_in[9];
  const float* f2W    = (const float*)d_in[10];
  const float* f2B    = (const float*)d_in[11];
  const float* qW     = (const float*)d_in[12];
  const float* qB     = (const float*)d_in[13];
  const float* kW     = (const float*)d_in[14];
  const float* kB     = (const float*)d_in[15];

  float* Xout = (float*)d_out;
  float* Tout = (float*)d_out + (size_t)BB * NN * CC;

  char* ws = (char*)d_ws;
  size_t off = 0;
  auto alloc_f = [&](size_t n) { float* pp = (float*)(ws + off); off += n * 4; return pp; };
  float* Tbuf   = alloc_f(524288);
  float* kqbuf  = alloc_f(524288);
  float* Tdash  = alloc_f(524288);
  float* rbuf   = alloc_f(1024);
  float* biaskq = alloc_f(1024);
  float* Mloc   = alloc_f(8192);
  float* Sloc   = alloc_f(8192);
  auto alloc_h = [&](size_t n) { unsigned short* pp = (unsigned short*)(ws + off); off += n * 2; return pp; };
  unsigned short* Tp     = alloc_h(8388608);   // [B][16][L][C] bf16
  unsigned short* Tbf    = alloc_h(524288);
  unsigned short* Tdbf   = alloc_h(524288);
  unsigned short* Hbf    = alloc_h(524288);
  unsigned short* Toutbf = alloc_h(524288);
  unsigned short* Tkbf   = alloc_h(524288);
  unsigned short* Gtbf   = alloc_h(524288);
  unsigned short* WkqT   = alloc_h(1048576);
  unsigned short* f1WT   = alloc_h(1048576);
  unsigned short* f2WT   = alloc_h(1048576);
  unsigned short* kWT    = alloc_h(1048576);
  unsigned short* qWbf   = alloc_h(1048576);
  unsigned short* tokWT  = alloc_h(16384);
  (void)ws_size; (void)in_sizes; (void)n_in; (void)out_size;

  wprep<<<dim3(32, 32, 6), dim3(32, 8), 0, stream>>>(keyW, queryW, f1W, f2W, kW, qW,
                                                     tokW, keyB, queryB,
                                                     WkqT, f1WT, f2WT, kWT, qWbf, tokWT, biaskq);
  tok_fused<<<dim3(16, 32), 256, 0, stream>>>(X, tokWT, tokB, Tp, Mloc, Sloc);
  tmerge<<<256, 256, 0, stream>>>(Tp, Mloc, Sloc, Tbuf, Tbf);
  gemm32x64<0,1,0,1,0><<<dim3(16, 16), 256, 0, stream>>>(Tbf, WkqT, biaskq, nullptr, kqbuf, nullptr);
  scores_tdash<<<dim3(8, 32), 256, 0, stream>>>(kqbuf, Tbuf, Tdash, Tdbf);
  gemm32x64<1,1,0,0,1><<<dim3(16, 16), 256, 0, stream>>>(Tdbf, f1WT, f1B, nullptr, nullptr, Hbf);
  gemm32x64<0,1,1,1,1><<<dim3(16, 16), 256, 0, stream>>>(Hbf, f2WT, f2B, Tdash, Tout, Toutbf);
  gemm32x64<0,1,0,0,1><<<dim3(16, 16), 256, 0, stream>>>(Toutbf, kWT, kB, nullptr, nullptr, Tkbf);
  r_kernel<<<128, 256, 0, stream>>>(Tkbf, qB, rbuf);
  gemm32x64<0,0,0,0,1><<<dim3(16, 16), 256, 0, stream>>>(Tkbf, qWbf, nullptr, nullptr, nullptr, Gtbf);
  sim_out_kernel<<<dim3(16, 32), 256, 0, stream>>>(X, Gtbf, rbuf, Tout, Xout);
}

// Round 9
// 175.896 us; speedup vs baseline: 2.4023x; 1.0129x over previous
//
#include <hip/hip_runtime.h>
#include <hip/hip_bf16.h>
#include <stdint.h>

#define BB 32
#define NN 1024
#define CC 1024
#define LL 16

typedef __attribute__((ext_vector_type(4))) float f32x4;
typedef __attribute__((ext_vector_type(8))) short short8;
typedef __attribute__((ext_vector_type(4))) unsigned short ushort4v;

__device__ __forceinline__ unsigned short f2bf(float f) {
  union { float f; unsigned u; } v; v.f = f;
  unsigned r = v.u + 0x7FFF + ((v.u >> 16) & 1);
  return (unsigned short)(r >> 16);
}
__device__ __forceinline__ float bf2f(unsigned short h) {
  union { unsigned u; float f; } v; v.u = ((unsigned)h) << 16; return v.f;
}
__device__ __forceinline__ short8 cvt8(f32x4 a, f32x4 b) {
  short8 r;
  r[0] = (short)f2bf(a[0]); r[1] = (short)f2bf(a[1]);
  r[2] = (short)f2bf(a[2]); r[3] = (short)f2bf(a[3]);
  r[4] = (short)f2bf(b[0]); r[5] = (short)f2bf(b[1]);
  r[6] = (short)f2bf(b[2]); r[7] = (short)f2bf(b[3]);
  return r;
}

// ---------------- weight prep: transpose->bf16 (+ tokW^T, bias pack at z=5) ----------------
__global__ __launch_bounds__(256) void wprep(
    const float* __restrict__ keyW, const float* __restrict__ queryW,
    const float* __restrict__ f1W, const float* __restrict__ f2W,
    const float* __restrict__ kW, const float* __restrict__ qW,
    const float* __restrict__ tokW, const float* __restrict__ keyb,
    const float* __restrict__ queryb,
    unsigned short* __restrict__ WkqT, unsigned short* __restrict__ f1WT,
    unsigned short* __restrict__ f2WT, unsigned short* __restrict__ kWT,
    unsigned short* __restrict__ qWbf, unsigned short* __restrict__ tokWT,
    float* __restrict__ biaskq)
{
  int z = blockIdx.z;
  int tx = threadIdx.x, ty = threadIdx.y;
  if (z == 5) {
    int gid = (blockIdx.y * 32 + blockIdx.x) * 256 + ty * 32 + tx;
    if (gid < 16384) {
      int l = gid >> 10, c = gid & 1023;
      tokWT[gid] = f2bf(tokW[c * 16 + l]);
    } else if (gid < 17408) {
      int i = gid - 16384;
      biaskq[i] = (i < 512) ? keyb[i] : queryb[i - 512];
    }
    return;
  }
  if (z == 4) {
#pragma unroll
    for (int i = 0; i < 4; ++i) {
      int row = blockIdx.y * 32 + ty + 8 * i;
      int col = blockIdx.x * 32 + tx;
      qWbf[row * 1024 + col] = f2bf(qW[row * 1024 + col]);
    }
    return;
  }
  __shared__ float tile[32][33];
  int j0 = blockIdx.x * 32, k0 = blockIdx.y * 32;
  const float* src = (z == 1) ? f1W : (z == 2) ? f2W : kW;
#pragma unroll
  for (int i = 0; i < 4; ++i) {
    int k = k0 + ty + 8 * i;
    int j = j0 + tx;
    float v;
    if (z == 0) v = (j < 512) ? keyW[k * 512 + j] : queryW[k * 512 + (j - 512)];
    else        v = src[k * 1024 + j];
    tile[ty + 8 * i][tx] = v;
  }
  __syncthreads();
  unsigned short* dst = (z == 0) ? WkqT : (z == 1) ? f1WT : (z == 2) ? f2WT : kWT;
#pragma unroll
  for (int i = 0; i < 4; ++i) {
    int j = j0 + ty + 8 * i;
    dst[j * 1024 + k0 + tx] = f2bf(tile[tx][ty + 8 * i]);
  }
}

// ---------------- fused tokenizer: direct-frag proj MFMA + chunk softmax + partial T ----------------
__global__ __launch_bounds__(256) void tok_fused(
    const float* __restrict__ X, const unsigned short* __restrict__ tokWT,
    const float* __restrict__ tokB, unsigned short* __restrict__ Tp,
    float* __restrict__ Mloc, float* __restrict__ Sloc)
{
  __shared__ float E[64][16];
  __shared__ float redm[4][16];
  __shared__ float reds[4][16];
  int tid = threadIdx.x, wid = tid >> 6, lane = tid & 63;
  int lr = lane & 15, hi = lane >> 4;
  int b = blockIdx.y, ch = blockIdx.x;
  int pix0 = b * 1024 + ch * 64;
  // phase 1: S = X @ tokW^T via direct-fragment MFMA (wave handles 16 rows)
  const float* Ar = X + (size_t)(pix0 + wid * 16 + lr) * 1024 + hi * 8;
  const unsigned short* Br = tokWT + lr * 1024 + hi * 8;
  f32x4 acc = (f32x4)0.f;
#pragma unroll 8
  for (int k0 = 0; k0 < 1024; k0 += 32) {
    f32x4 x0 = *(const f32x4*)(Ar + k0);
    f32x4 x1 = *(const f32x4*)(Ar + k0 + 4);
    short8 bfrag = *(const short8*)(Br + k0);
    acc = __builtin_amdgcn_mfma_f32_16x16x32_bf16(cvt8(x0, x1), bfrag, acc, 0, 0, 0);
  }
  // chunk-local softmax partials per column l=lr; lane holds rows wid*16+hi*4+rr
  float tb = tokB[lr];
  float sv[4];
#pragma unroll
  for (int rr = 0; rr < 4; ++rr) sv[rr] = acc[rr] + tb;
  float pm = fmaxf(fmaxf(sv[0], sv[1]), fmaxf(sv[2], sv[3]));
  pm = fmaxf(pm, __shfl_xor(pm, 16));
  pm = fmaxf(pm, __shfl_xor(pm, 32));
  if (hi == 0) redm[wid][lr] = pm;
  __syncthreads();
  float m = fmaxf(fmaxf(redm[0][lr], redm[1][lr]), fmaxf(redm[2][lr], redm[3][lr]));
  float ev[4]; float ps = 0.f;
#pragma unroll
  for (int i = 0; i < 4; ++i) { ev[i] = __expf(sv[i] - m); ps += ev[i]; }
  ps += __shfl_xor(ps, 16); ps += __shfl_xor(ps, 32);
  if (hi == 0) reds[wid][lr] = ps;
#pragma unroll
  for (int rr = 0; rr < 4; ++rr)
    E[wid * 16 + hi * 4 + rr][lr] = ev[rr];
  __syncthreads();
  if (tid < 16) {
    float sl = reds[0][tid] + reds[1][tid] + reds[2][tid] + reds[3][tid];
    Mloc[(b * 16 + ch) * 16 + tid] = m;
    Sloc[(b * 16 + ch) * 16 + tid] = sl;
  }
  // phase 2: partial T[l][c] = sum_n E[n][l] * X[n][c]  (chunk L2-hot)
  f32x4 a16[16];
#pragma unroll
  for (int l = 0; l < 16; ++l) a16[l] = (f32x4)0.f;
  const float* xp = X + (size_t)pix0 * 1024 + tid * 4;
  for (int n0 = 0; n0 < 64; n0 += 8) {
    f32x4 xv[8];
#pragma unroll
    for (int i = 0; i < 8; ++i) xv[i] = *(const f32x4*)(xp + (size_t)(n0 + i) * 1024);
#pragma unroll
    for (int i = 0; i < 8; ++i) {
      const f32x4* ar = (const f32x4*)&E[n0 + i][0];
      f32x4 a0 = ar[0], a1 = ar[1], a2 = ar[2], a3 = ar[3];
      f32x4 x0 = xv[i];
      a16[0]  += a0[0]*x0; a16[1]  += a0[1]*x0; a16[2]  += a0[2]*x0; a16[3]  += a0[3]*x0;
      a16[4]  += a1[0]*x0; a16[5]  += a1[1]*x0; a16[6]  += a1[2]*x0; a16[7]  += a1[3]*x0;
      a16[8]  += a2[0]*x0; a16[9]  += a2[1]*x0; a16[10] += a2[2]*x0; a16[11] += a2[3]*x0;
      a16[12] += a3[0]*x0; a16[13] += a3[1]*x0; a16[14] += a3[2]*x0; a16[15] += a3[3]*x0;
    }
  }
  unsigned short* op = Tp + ((size_t)(b * 16 + ch) * 16) * 1024 + tid * 4;
#pragma unroll
  for (int l = 0; l < 16; ++l) {
    f32x4 s = a16[l];
    ushort4v h; h[0]=f2bf(s[0]); h[1]=f2bf(s[1]); h[2]=f2bf(s[2]); h[3]=f2bf(s[3]);
    *(ushort4v*)(op + (size_t)l * 1024) = h;
  }
}

// ---------------- merge 16 chunk partials with online-softmax rescale ----------------
__global__ __launch_bounds__(256) void tmerge(
    const unsigned short* __restrict__ Tp, const float* __restrict__ Mloc,
    const float* __restrict__ Sloc, float* __restrict__ T,
    unsigned short* __restrict__ Tbf)
{
  int tid = threadIdx.x;
  int g = blockIdx.x * 2 + (tid >> 7);    // token row in [0,512)
  int b = g >> 4, l = g & 15;
  int j = tid & 127;
  float M = -1e30f;
#pragma unroll
  for (int ch = 0; ch < 16; ++ch) M = fmaxf(M, Mloc[(b * 16 + ch) * 16 + l]);
  float w[16]; float denom = 0.f;
#pragma unroll
  for (int ch = 0; ch < 16; ++ch) {
    w[ch] = __expf(Mloc[(b * 16 + ch) * 16 + l] - M);
    denom += w[ch] * Sloc[(b * 16 + ch) * 16 + l];
  }
  float inv = 1.f / denom;
  float o[8];
#pragma unroll
  for (int t = 0; t < 8; ++t) o[t] = 0.f;
#pragma unroll
  for (int ch = 0; ch < 16; ++ch) {
    const unsigned short* p = Tp + ((size_t)((b * 16 + ch) * 16 + l)) * 1024 + j * 8;
    short8 v = *(const short8*)p;
    float wc = w[ch];
#pragma unroll
    for (int t = 0; t < 8; ++t) o[t] += wc * bf2f((unsigned short)v[t]);
  }
  f32x4 o0, o1; short8 hb;
#pragma unroll
  for (int t = 0; t < 4; ++t) {
    float x0 = o[t] * inv, x1 = o[4 + t] * inv;
    o0[t] = x0; o1[t] = x1;
    hb[t] = (short)f2bf(x0); hb[4 + t] = (short)f2bf(x1);
  }
  *(f32x4*)(T + (size_t)g * 1024 + j * 8) = o0;
  *(f32x4*)(T + (size_t)g * 1024 + j * 8 + 4) = o1;
  *(short8*)(Tbf + (size_t)g * 1024 + j * 8) = hb;
}

// ---------------- NT bf16 GEMM, M=512, Nn=1024, K=1024, 32x64 tiles ----------------
template<int RELU, int HAS_BIAS, int HAS_RES, int STORE_F32, int STORE_BF16>
__global__ __launch_bounds__(256) void gemm32x64(
    const unsigned short* __restrict__ A, const unsigned short* __restrict__ Bm,
    const float* __restrict__ bias, const float* __restrict__ res,
    float* __restrict__ outF, unsigned short* __restrict__ outB)
{
  const int K = 1024;
  __shared__ __align__(16) char sh[12288];   // As 4KB | Bs 8KB, XOR-swizzled rows of 128B
  char* Asp = sh;
  char* Bsp = sh + 4096;
  int tid = threadIdx.x, wid = tid >> 6, lane = tid & 63;
  int lr = lane & 15, hi = lane >> 4;
  int m0 = blockIdx.x * 32, n0 = blockIdx.y * 64;
  int arow = tid >> 3, acol = (tid & 7) * 8;   // A stage: 32x64
  int brow = tid >> 2, bcol = (tid & 3) * 16;  // B stage: 64x64
  const unsigned short* Ap = A + (size_t)(m0 + arow) * K + acol;
  const unsigned short* Bp = Bm + (size_t)(n0 + brow) * K + bcol;
  int aw  = arow * 128 + (((acol * 2) ^ ((arow & 7) << 4)));
  int bw0 = brow * 128 + (((bcol * 2) ^ ((brow & 7) << 4)));
  int bw1 = brow * 128 + ((((bcol * 2) + 16) ^ ((brow & 7) << 4)));
  short8 aR[2]; short8 bR[2][2];
  aR[0]    = *(const short8*)(Ap);
  bR[0][0] = *(const short8*)(Bp);
  bR[0][1] = *(const short8*)(Bp + 8);
  aR[1]    = *(const short8*)(Ap + 64);
  bR[1][0] = *(const short8*)(Bp + 64);
  bR[1][1] = *(const short8*)(Bp + 72);
  f32x4 acc[2];
  acc[0] = (f32x4)0.f; acc[1] = (f32x4)0.f;
  int wm = (wid >> 1) * 16, wn = (wid & 1) * 32;
  int arb = (wm + lr) * 128, arx = ((wm + lr) & 7) << 4;
  for (int s = 0; s < 16; ++s) {
    __syncthreads();
    *(short8*)(Asp + aw)  = aR[s & 1];
    *(short8*)(Bsp + bw0) = bR[s & 1][0];
    *(short8*)(Bsp + bw1) = bR[s & 1][1];
    __syncthreads();
    if (s + 2 < 16) {
      int k0 = (s + 2) * 64;
      aR[s & 1]    = *(const short8*)(Ap + k0);
      bR[s & 1][0] = *(const short8*)(Bp + k0);
      bR[s & 1][1] = *(const short8*)(Bp + k0 + 8);
    }
#pragma unroll
    for (int kk = 0; kk < 2; ++kk) {
      short8 af = *(const short8*)(Asp + arb + (((kk * 64 + hi * 16) ^ arx)));
#pragma unroll
      for (int sn = 0; sn < 2; ++sn) {
        int br = wn + sn * 16 + lr;
        short8 bf = *(const short8*)(Bsp + br * 128 + (((kk * 64 + hi * 16) ^ ((br & 7) << 4))));
        acc[sn] = __builtin_amdgcn_mfma_f32_16x16x32_bf16(af, bf, acc[sn], 0, 0, 0);
      }
    }
  }
  int row0 = m0 + wm + hi * 4;
#pragma unroll
  for (int sn = 0; sn < 2; ++sn) {
    int col = n0 + wn + sn * 16 + lr;
    float bv_ = HAS_BIAS ? bias[col] : 0.f;
#pragma unroll
    for (int rr = 0; rr < 4; ++rr) {
      float x = acc[sn][rr] + bv_;
      if (RELU) x = fmaxf(x, 0.f);
      size_t idx = (size_t)(row0 + rr) * 1024 + col;
      if (HAS_RES) x += res[idx];
      if (STORE_F32) outF[idx] = x;
      if (STORE_BF16) outB[idx] = f2bf(x);
    }
  }
}

// ---------------- token self-attn: scores + softmax + T_dash (c-split 8) ----------------
__global__ __launch_bounds__(256) void scores_tdash(
    const float* __restrict__ kq, const float* __restrict__ T,
    float* __restrict__ Tdash, unsigned short* __restrict__ Tdbf)
{
  int cs = blockIdx.x, b = blockIdx.y;
  int c0 = cs * 128;
  __shared__ float Ts[16][128];
  int tid = threadIdx.x, lane = tid & 63;
#pragma unroll
  for (int i = 0; i < 2; ++i) {
    int fi = tid + 256 * i;            // f4 over 512
    int rrow = fi >> 5, c4 = (fi & 31) * 4;
    *(f32x4*)&Ts[rrow][c4] = *(const f32x4*)&T[((size_t)b * 16 + rrow) * 1024 + c0 + c4];
  }
  __syncthreads();
  int l = tid >> 4, m = tid & 15;
  const float* krow = kq + ((size_t)b * 16 + l) * 1024;
  const float* qrow = kq + ((size_t)b * 16 + m) * 1024 + 512;
  float s = 0.f;
#pragma unroll 8
  for (int d = 0; d < 512; d += 4) {
    f32x4 kv = *(const f32x4*)(krow + d);
    f32x4 qv = *(const f32x4*)(qrow + d);
    s += kv[0]*qv[0] + kv[1]*qv[1] + kv[2]*qv[2] + kv[3]*qv[3];
  }
  float mx = s;
  mx = fmaxf(mx, __shfl_xor(mx, 1)); mx = fmaxf(mx, __shfl_xor(mx, 2));
  mx = fmaxf(mx, __shfl_xor(mx, 4)); mx = fmaxf(mx, __shfl_xor(mx, 8));
  float e = __expf(s - mx);
  float sum = e;
  sum += __shfl_xor(sum, 1); sum += __shfl_xor(sum, 2);
  sum += __shfl_xor(sum, 4); sum += __shfl_xor(sum, 8);
  float pv = e / sum;
  float pl[16];
#pragma unroll
  for (int i = 0; i < 16; ++i) pl[i] = __shfl(pv, (lane & 48) + i);
  float* od = Tdash + ((size_t)b * 16 + l) * 1024 + c0;
  unsigned short* ob = Tdbf + ((size_t)b * 16 + l) * 1024 + c0;
#pragma unroll
  for (int h = 0; h < 2; ++h) {
    int c = m * 8 + h * 4;
    f32x4 o = *(const f32x4*)&Ts[l][c];
#pragma unroll
    for (int mm = 0; mm < 16; ++mm) {
      f32x4 tv = *(const f32x4*)&Ts[mm][c];
      o += pl[mm] * tv;
    }
    *(f32x4*)(od + c) = o;
    ushort4v hh; hh[0]=f2bf(o[0]); hh[1]=f2bf(o[1]); hh[2]=f2bf(o[2]); hh[3]=f2bf(o[3]);
    *(ushort4v*)(ob + c) = hh;
  }
}

// ---------------- r[b,l] = q_b . Tk[b,l,:] ----------------
__global__ __launch_bounds__(256) void r_kernel(
    const unsigned short* __restrict__ Tkbf, const float* __restrict__ qb,
    float* __restrict__ r)
{
  int row = blockIdx.x * 4 + (threadIdx.x >> 6);
  int lane = threadIdx.x & 63;
  const unsigned short* p = Tkbf + (size_t)row * CC;
  float s = 0.f;
#pragma unroll
  for (int h = 0; h < 2; ++h) {
    int d0 = lane * 8 + h * 512;
    short8 v = *(const short8*)&p[d0];
#pragma unroll
    for (int jj = 0; jj < 8; ++jj)
      s += bf2f((unsigned short)v[jj]) * qb[d0 + jj];
  }
#pragma unroll
  for (int msk = 32; msk >= 1; msk >>= 1) s += __shfl_xor(s, msk);
  if (lane == 0) r[row] = s;
}

// ---------------- fused sim + out: direct-frag MFMA, P in LDS, X_out = X + P@T_out ----------------
__global__ __launch_bounds__(256) void sim_out_kernel(
    const float* __restrict__ X, const unsigned short* __restrict__ Gt,
    const float* __restrict__ rbias, const float* __restrict__ Tout,
    float* __restrict__ Xout)
{
  __shared__ float Ps[64][16];
  int tid = threadIdx.x, wid = tid >> 6, lane = tid & 63;
  int lr = lane & 15, hi = lane >> 4;
  int b = blockIdx.y;
  int pix0 = b * 1024 + blockIdx.x * 64;
  const float* Ar = X + (size_t)(pix0 + wid * 16 + lr) * 1024 + hi * 8;
  const unsigned short* Br = Gt + (size_t)b * 16384 + lr * 1024 + hi * 8;
  f32x4 acc = (f32x4)0.f;
#pragma unroll 8
  for (int k0 = 0; k0 < 1024; k0 += 32) {
    f32x4 x0 = *(const f32x4*)(Ar + k0);
    f32x4 x1 = *(const f32x4*)(Ar + k0 + 4);
    short8 bfrag = *(const short8*)(Br + k0);
    acc = __builtin_amdgcn_mfma_f32_16x16x32_bf16(cvt8(x0, x1), bfrag, acc, 0, 0, 0);
  }
  // in-register softmax over l (16-lane groups), P -> LDS
  float bv = rbias[b * 16 + lr];
  int prow = wid * 16 + hi * 4;
#pragma unroll
  for (int rr = 0; rr < 4; ++rr) {
    float vv = acc[rr] + bv;
    float mx = vv;
    mx = fmaxf(mx, __shfl_xor(mx, 1)); mx = fmaxf(mx, __shfl_xor(mx, 2));
    mx = fmaxf(mx, __shfl_xor(mx, 4)); mx = fmaxf(mx, __shfl_xor(mx, 8));
    float e = __expf(vv - mx);
    float ss = e;
    ss += __shfl_xor(ss, 1); ss += __shfl_xor(ss, 2);
    ss += __shfl_xor(ss, 4); ss += __shfl_xor(ss, 8);
    Ps[prow + rr][lr] = e / ss;
  }
  __syncthreads();
  // phase 2: X_out = X + P @ T_out, T_out column-slice in registers
  int c4 = tid * 4;
  f32x4 tsr[16];
#pragma unroll
  for (int l = 0; l < 16; ++l)
    tsr[l] = *(const f32x4*)&Tout[((size_t)b * 16 + l) * 1024 + c4];
  const float* xp = X + (size_t)pix0 * 1024 + c4;
  float* op = Xout + (size_t)pix0 * 1024 + c4;
#pragma unroll 2
  for (int n = 0; n < 64; ++n) {
    f32x4 xv = *(const f32x4*)(xp + (size_t)n * 1024);
    const f32x4* pr = (const f32x4*)&Ps[n][0];
    f32x4 p0 = pr[0], p1 = pr[1], p2 = pr[2], p3 = pr[3];
    f32x4 o = xv;
    o += p0[0]*tsr[0];  o += p0[1]*tsr[1];  o += p0[2]*tsr[2];  o += p0[3]*tsr[3];
    o += p1[0]*tsr[4];  o += p1[1]*tsr[5];  o += p1[2]*tsr[6];  o += p1[3]*tsr[7];
    o += p2[0]*tsr[8];  o += p2[1]*tsr[9];  o += p2[2]*tsr[10]; o += p2[3]*tsr[11];
    o += p3[0]*tsr[12]; o += p3[1]*tsr[13]; o += p3[2]*tsr[14]; o += p3[3]*tsr[15];
    __builtin_nontemporal_store(o, (f32x4*)(op + (size_t)n * 1024));
  }
}

extern "C" void kernel_launch(void* const* d_in, const int* in_sizes, int n_in,
                              void* d_out, int out_size, void* d_ws, size_t ws_size,
                              hipStream_t stream)
{
  const float* X      = (const float*)d_in[0];
  const float* tokW   = (const float*)d_in[2];
  const float* tokB   = (const float*)d_in[3];
  const float* keyW   = (const float*)d_in[4];
  const float* keyB   = (const float*)d_in[5];
  const float* queryW = (const float*)d_in[6];
  const float* queryB = (const float*)d_in[7];
  const float* f1W    = (const float*)d_in[8];
  const float* f1B    = (const float*)d_in[9];
  const float* f2W    = (const float*)d_in[10];
  const float* f2B    = (const float*)d_in[11];
  const float* qW     = (const float*)d_in[12];
  const float* qB     = (const float*)d_in[13];
  const float* kW     = (const float*)d_in[14];
  const float* kB     = (const float*)d_in[15];

  float* Xout = (float*)d_out;
  float* Tout = (float*)d_out + (size_t)BB * NN * CC;

  char* ws = (char*)d_ws;
  size_t off = 0;
  auto alloc_f = [&](size_t n) { float* pp = (float*)(ws + off); off += n * 4; return pp; };
  float* Tbuf   = alloc_f(524288);
  float* kqbuf  = alloc_f(524288);
  float* Tdash  = alloc_f(524288);
  float* rbuf   = alloc_f(1024);
  float* biaskq = alloc_f(1024);
  float* Mloc   = alloc_f(8192);
  float* Sloc   = alloc_f(8192);
  auto alloc_h = [&](size_t n) { unsigned short* pp = (unsigned short*)(ws + off); off += n * 2; return pp; };
  unsigned short* Tp     = alloc_h(8388608);   // [B][16][L][C] bf16
  unsigned short* Tbf    = alloc_h(524288);
  unsigned short* Tdbf   = alloc_h(524288);
  unsigned short* Hbf    = alloc_h(524288);
  unsigned short* Toutbf = alloc_h(524288);
  unsigned short* Tkbf   = alloc_h(524288);
  unsigned short* Gtbf   = alloc_h(524288);
  unsigned short* WkqT   = alloc_h(1048576);
  unsigned short* f1WT   = alloc_h(1048576);
  unsigned short* f2WT   = alloc_h(1048576);
  unsigned short* kWT    = alloc_h(1048576);
  unsigned short* qWbf   = alloc_h(1048576);
  unsigned short* tokWT  = alloc_h(16384);
  (void)ws_size; (void)in_sizes; (void)n_in; (void)out_size;

  wprep<<<dim3(32, 32, 6), dim3(32, 8), 0, stream>>>(keyW, queryW, f1W, f2W, kW, qW,
                                                     tokW, keyB, queryB,
                                                     WkqT, f1WT, f2WT, kWT, qWbf, tokWT, biaskq);
  tok_fused<<<dim3(16, 32), 256, 0, stream>>>(X, tokWT, tokB, Tp, Mloc, Sloc);
  tmerge<<<256, 256, 0, stream>>>(Tp, Mloc, Sloc, Tbuf, Tbf);
  gemm32x64<0,1,0,1,0><<<dim3(16, 16), 256, 0, stream>>>(Tbf, WkqT, biaskq, nullptr, kqbuf, nullptr);
  scores_tdash<<<dim3(8, 32), 256, 0, stream>>>(kqbuf, Tbuf, Tdash, Tdbf);
  gemm32x64<1,1,0,0,1><<<dim3(16, 16), 256, 0, stream>>>(Tdbf, f1WT, f1B, nullptr, nullptr, Hbf);
  gemm32x64<0,1,1,1,1><<<dim3(16, 16), 256, 0, stream>>>(Hbf, f2WT, f2B, Tdash, Tout, Toutbf);
  gemm32x64<0,1,0,0,1><<<dim3(16, 16), 256, 0, stream>>>(Toutbf, kWT, kB, nullptr, nullptr, Tkbf);
  r_kernel<<<128, 256, 0, stream>>>(Tkbf, qB, rbuf);
  gemm32x64<0,0,0,0,1><<<dim3(16, 16), 256, 0, stream>>>(Tkbf, qWbf, nullptr, nullptr, nullptr, Gtbf);
  sim_out_kernel<<<dim3(16, 32), 256, 0, stream>>>(X, Gtbf, rbuf, Tout, Xout);
}